// Round 16
// baseline (321.743 us; speedup 1.0000x reference)
//
#include <hip/hip_runtime.h>
#include <math.h>

#define L 9216
#define HH 96
#define WW 96
#define CC 256
#define CR 64
#define NCLUST 128
#define WIN 144
#define NK 64   // L/WIN

typedef float f32x4 __attribute__((ext_vector_type(4)));
typedef float f32x16 __attribute__((ext_vector_type(16)));
typedef short s8v __attribute__((ext_vector_type(8)));
typedef short s4v __attribute__((ext_vector_type(4)));

static __device__ __forceinline__ short f2bf(float x) {
  union { float f; unsigned u; } v; v.f = x;
  unsigned r = (v.u + 0x7FFF + ((v.u >> 16) & 1)) >> 16;
  return (short)r;
}
static __device__ __forceinline__ float bf2f(short h) {
  union { float f; unsigned u; } v;
  v.u = ((unsigned)(unsigned short)h) << 16;
  return v.f;
}

// ---------------- K0a: input split fp32 -> xhi/xlo bf16, layout [b][h][icc16][w96][ic16] ----------------
__global__ __launch_bounds__(256) void k_isplit(const float* __restrict__ in,
                                                unsigned short* __restrict__ xhi,
                                                unsigned short* __restrict__ xlo) {
  int h = blockIdx.x, icc = blockIdx.y, b = blockIdx.z;
  __shared__ float tile[16][97];
  int t = threadIdx.x;
  for (int e = t; e < 1536; e += 256) {
    int ic = e / 96, w = e % 96;
    tile[ic][w] = in[((size_t)(b * 256 + icc * 16 + ic)) * L + h * 96 + w];
  }
  __syncthreads();
  size_t base = (((size_t)b * 96 + h) * 16 + icc) * 1536;
  for (int e = t; e < 1536; e += 256) {
    int w = e >> 4, ic = e & 15;
    float v = tile[ic][w];
    short hi = f2bf(v);
    float rv = v - bf2f(hi);
    short lo = f2bf(rv);
    xhi[base + e] = (unsigned short)hi;
    xlo[base + e] = (unsigned short)lo;
  }
}

// ---------------- K0b: conv3 weight split -> whiB/wloB [icc][tap][oc64][ic16] bf16 ----------------
__global__ __launch_bounds__(256) void k_wsplit(const float* __restrict__ wm,
                                                unsigned short* __restrict__ whiB,
                                                unsigned short* __restrict__ wloB) {
  int idx = blockIdx.x * 256 + threadIdx.x;
  if (idx < 147456) {
    int ic = idx & 15;
    int oc = (idx >> 4) & 63;
    int g = idx >> 10;
    int tap = g % 9, icc = g / 9;
    float v = wm[(size_t)oc * 2304 + (icc * 16 + ic) * 9 + tap];
    short hi = f2bf(v);
    float rv = v - bf2f(hi);
    whiB[idx] = (unsigned short)hi;
    wloB[idx] = (unsigned short)f2bf(rv);
  }
}

// ---------------- K0c: conv1 weight prep -> wt1 [icc][oc256][ic16] bf16 ----------------
__global__ __launch_bounds__(256) void k_w1prep(const float* __restrict__ wa,
                                                unsigned short* __restrict__ wt1) {
  int idx = blockIdx.x * 256 + threadIdx.x;  // 65536 total
  int ic = idx & 15, oc = (idx >> 4) & 255, icc = idx >> 12;
  wt1[idx] = (unsigned short)f2bf(wa[(size_t)oc * 256 + icc * 16 + ic]);
}

// ---------------- K1: conv3x3 via MFMA (split-bf16, 3 products), 2 rows/wave, ich-split ----------------
// grid 768 linear: b = i&7 (XCD affinity); v = i>>3; hp = v%48 (row pair), ich = v/48.
// 192 thr = 3 waves; wave pt owns 32 px x 64 oc x 2 rows (B-frags shared across rows ->
// L2 line traffic per row halved). 8 chunks of 16 ic per block; ich==1 -> xpart partials.
__global__ __launch_bounds__(192) void k_conv3(const unsigned short* __restrict__ xhi,
                                               const unsigned short* __restrict__ xlo,
                                               const unsigned short* __restrict__ whiB,
                                               const unsigned short* __restrict__ wloB,
                                               const float* __restrict__ bm,
                                               float* __restrict__ xe,
                                               float* __restrict__ xpart) {
  int i = blockIdx.x;
  int b = i & 7;
  int v = i >> 3;
  int hp = v % 48, ich = v / 48;
  int h0 = hp * 2;
  int icc0 = ich * 8;
  // [buf][split][row4][col98][ic16]; strides: buf 12544, split 6272, row 1568
  __shared__ __align__(16) unsigned short lds[25088];  // 50176 B
  int t = threadIdx.x;
  int pt = t >> 6, lane = t & 63;
  int hh = lane >> 5, j = lane & 31;
  int r = lane & 31;

  // zero the halo column slots (0 and 97) of all 2x2x4 planes
  for (int e = t; e < 512; e += 192) {
    int ic = e & 15, slot = e >> 4;  // 32 slots
    int bs = slot >> 4, rem = slot & 15;
    int s = rem >> 3, rem2 = rem & 7;
    int rr = rem2 >> 1, cc = rem2 & 1;
    lds[bs * 12544 + s * 6272 + rr * 1568 + (cc ? 97 : 0) * 16 + ic] = 0;
  }

  f32x16 acc[4] = {};

  auto stage = [&](int icc, int buf) {
#pragma unroll
    for (int k8 = 0; k8 < 8; ++k8) {
      int u = t + k8 * 192;            // 0..1536
      int s = u / 768;
      int rem = u - s * 768;
      int rr = rem / 192;
      int q = rem - rr * 192;
      int gr = h0 - 1 + rr;
      unsigned short* dst = &lds[buf * 12544 + s * 6272 + rr * 1568 + 16 + q * 8];
      if (gr >= 0 && gr < 96) {
        const unsigned short* src =
            (s ? xlo : xhi) + ((((size_t)b * 96 + gr) * 16 + icc) * 1536 + q * 8);
        __builtin_amdgcn_global_load_lds((const __attribute__((address_space(1))) void*)src,
                                         (__attribute__((address_space(3))) void*)dst, 16, 0, 0);
      } else {
        *(s8v*)dst = (s8v){0, 0, 0, 0, 0, 0, 0, 0};
      }
    }
  };

  auto compute = [&](int icc, int buf) {
    const unsigned short* lbase = lds + buf * 12544;
    const unsigned short* wb = whiB + (size_t)icc * 9216;
    const unsigned short* wl = wloB + (size_t)icc * 9216;
#pragma unroll
    for (int kh = 0; kh < 3; ++kh)
#pragma unroll
      for (int kw = 0; kw < 3; ++kw) {
        int tap = kh * 3 + kw;
        int woff = tap * 1024 + j * 16 + hh * 8;
        s8v b_hi0 = *(const s8v*)(wb + woff);
        s8v b_lo0 = *(const s8v*)(wl + woff);
        s8v b_hi1 = *(const s8v*)(wb + woff + 512);
        s8v b_lo1 = *(const s8v*)(wl + woff + 512);
#pragma unroll
        for (int rw = 0; rw < 2; ++rw) {
          int aidx = (rw + kh) * 1568 + (pt * 32 + r + kw) * 16 + hh * 8;
          s8v a_hi = *(const s8v*)(lbase + aidx);
          s8v a_lo = *(const s8v*)(lbase + 6272 + aidx);
          acc[rw * 2 + 0] = __builtin_amdgcn_mfma_f32_32x32x16_bf16(a_hi, b_hi0, acc[rw * 2 + 0], 0, 0, 0);
          acc[rw * 2 + 0] = __builtin_amdgcn_mfma_f32_32x32x16_bf16(a_hi, b_lo0, acc[rw * 2 + 0], 0, 0, 0);
          acc[rw * 2 + 0] = __builtin_amdgcn_mfma_f32_32x32x16_bf16(a_lo, b_hi0, acc[rw * 2 + 0], 0, 0, 0);
          acc[rw * 2 + 1] = __builtin_amdgcn_mfma_f32_32x32x16_bf16(a_hi, b_hi1, acc[rw * 2 + 1], 0, 0, 0);
          acc[rw * 2 + 1] = __builtin_amdgcn_mfma_f32_32x32x16_bf16(a_hi, b_lo1, acc[rw * 2 + 1], 0, 0, 0);
          acc[rw * 2 + 1] = __builtin_amdgcn_mfma_f32_32x32x16_bf16(a_lo, b_hi1, acc[rw * 2 + 1], 0, 0, 0);
        }
      }
  };

  stage(icc0, 0);
  __syncthreads();
#pragma unroll 1
  for (int c = 0; c < 8; ++c) {
    int buf = c & 1;
    if (c < 7) stage(icc0 + c + 1, buf ^ 1);
    compute(icc0 + c, buf);
    __syncthreads();
  }

  float* dst = ich ? xpart : xe;
  float bv0 = ich ? 0.f : bm[j];
  float bv1 = ich ? 0.f : bm[32 + j];
#pragma unroll
  for (int rw = 0; rw < 2; ++rw) {
#pragma unroll
    for (int reg = 0; reg < 16; ++reg) {
      int prow = (reg & 3) + 8 * (reg >> 2) + 4 * hh;
      size_t rowbase = ((size_t)b * L + (h0 + rw) * 96 + pt * 32 + prow) * 64;
      dst[rowbase + j] = acc[rw * 2 + 0][reg] + bv0;
      dst[rowbase + 32 + j] = acc[rw * 2 + 1][reg] + bv1;
    }
  }
}

// ---------------- K1b: x_embed += xpart ----------------
__global__ __launch_bounds__(256) void k_xred(float* __restrict__ xe,
                                              const float* __restrict__ xpart) {
  int idx = blockIdx.x * 256 + threadIdx.x;
  if (idx < 1179648) {
    f32x4 a = *(const f32x4*)&xe[idx * 4];
    a += *(const f32x4*)&xpart[idx * 4];
    *(f32x4*)&xe[idx * 4] = a;
  }
}

// ---------------- K2: conv1x1 via MFMA bf16 (no LDS, no barriers) ----------------
__global__ __launch_bounds__(384) void k_conv1(const unsigned short* __restrict__ xhi,
                                               const unsigned short* __restrict__ wt1,
                                               const float* __restrict__ ba,
                                               unsigned short* __restrict__ yeb) {
  int h = blockIdx.x, b = blockIdx.y;
  int t = threadIdx.x;
  int wave = t >> 6, lane = t & 63;
  int pt = wave % 3, ot = wave / 3;
  int hh = lane >> 5, j = lane & 31;
  int r = lane & 31;

  f32x16 acc[4] = {};
  const unsigned short* abase =
      xhi + (((size_t)b * 96 + h) * 16) * 1536 + (pt * 32 + r) * 16 + hh * 8;
  const unsigned short* bbase = wt1 + (ot * 128 + j) * 16 + hh * 8;
#pragma unroll 2
  for (int icc = 0; icc < 16; ++icc) {
    s8v av = *(const s8v*)(abase + icc * 1536);
    const unsigned short* bp = bbase + icc * 4096;
#pragma unroll
    for (int tile = 0; tile < 4; ++tile) {
      s8v bv = *(const s8v*)(bp + tile * 512);
      acc[tile] = __builtin_amdgcn_mfma_f32_32x32x16_bf16(av, bv, acc[tile], 0, 0, 0);
    }
  }
#pragma unroll
  for (int tile = 0; tile < 4; ++tile) {
    int oc = ot * 128 + tile * 32 + j;
    float bias = ba[oc];
#pragma unroll
    for (int reg = 0; reg < 16; ++reg) {
      int prow = (reg & 3) + 8 * (reg >> 2) + 4 * hh;
      yeb[((size_t)b * L + h * 96 + pt * 32 + prow) * 256 + oc] =
          (unsigned short)f2bf(acc[tile][reg] + bias);
    }
  }
}

// ---------------- K3: buckets = argmax_c(x . mean_c) ----------------
__global__ __launch_bounds__(256) void k_bucket(const float* __restrict__ xe,
                                                const float* __restrict__ means,
                                                int* __restrict__ buckets) {
  int lt = blockIdx.x, b = blockIdx.y;
  int l0 = lt * 32;
  __shared__ float x_s[32 * 65];
  __shared__ float m_s[128 * 65];
  __shared__ float bv_s[32 * 8];
  __shared__ int bi_s[32 * 8];
  int t = threadIdx.x;
  for (int e = t; e < 2048; e += 256) {
    int px = e >> 6, d = e & 63;
    x_s[px * 65 + d] = xe[((size_t)b * L + l0) * 64 + e];
  }
  for (int e = t; e < 8192; e += 256) {
    int c = e >> 6, d = e & 63;
    m_s[c * 65 + d] = means[e];
  }
  __syncthreads();
  int px = t >> 3, cg = t & 7;
  float best = -1e30f;
  int bidx = 0;
  const float* xr = &x_s[px * 65];
  for (int cc = 0; cc < 16; ++cc) {
    int c = cg + 8 * cc;
    const float* mr = &m_s[c * 65];
    float d = 0.f;
#pragma unroll
    for (int dd = 0; dd < 64; ++dd) d += xr[dd] * mr[dd];
    if (d > best || (d == best && c < bidx)) { best = d; bidx = c; }
  }
  bv_s[px * 8 + cg] = best;
  bi_s[px * 8 + cg] = bidx;
  __syncthreads();
  if (cg == 0) {
    float bb = bv_s[px * 8];
    int bbi = bi_s[px * 8];
    for (int g = 1; g < 8; ++g) {
      float v = bv_s[px * 8 + g];
      int vi = bi_s[px * 8 + g];
      if (v > bb || (v == bb && vi < bbi)) { bb = v; bbi = vi; }
    }
    buckets[b * L + l0 + px] = bbi;
  }
}

// ---------------- K4: parallel stable counting sort ----------------
#define SCH 256
#define CHL 36
__global__ __launch_bounds__(256) void k_sort(const int* __restrict__ buckets,
                                              int* __restrict__ sidx) {
  int b = blockIdx.x, t = threadIdx.x;
  __shared__ int keys_s[L];
  __shared__ unsigned short cnt_s[SCH][130];
  __shared__ int halfsum0[NCLUST];
  __shared__ int keytotal[NCLUST];
  __shared__ int keybase[NCLUST];
  const int* bk = buckets + b * L;
  for (int i = t; i < L; i += SCH) keys_s[i] = bk[i];
  for (int i = 0; i < 130; ++i) cnt_s[t][i] = 0;
  __syncthreads();
  {
    int base = t * CHL;
    for (int i = 0; i < CHL; ++i) cnt_s[t][keys_s[base + i]]++;
  }
  __syncthreads();
  {
    int kkey = t & 127, h = t >> 7;
    int c0 = h * 128;
    int run = 0;
    for (int c = 0; c < 128; ++c) {
      int v = cnt_s[c0 + c][kkey];
      cnt_s[c0 + c][kkey] = (unsigned short)run;
      run += v;
    }
    if (h == 0) halfsum0[kkey] = run;
    else keytotal[kkey] = run;
  }
  __syncthreads();
  if (t < NCLUST) keytotal[t] += halfsum0[t];
  __syncthreads();
  if (t == 0) {
    int s = 0;
    for (int i = 0; i < NCLUST; ++i) { keybase[i] = s; s += keytotal[i]; }
  }
  __syncthreads();
  {
    int h = t >> 7;
    int base = t * CHL;
    int* sb = sidx + b * L;
    for (int i = 0; i < CHL; ++i) {
      int kkey = keys_s[base + i];
      int pos = keybase[kkey] + (h ? halfsum0[kkey] : 0) + cnt_s[t][kkey];
      cnt_s[t][kkey]++;
      sb[pos] = base + i;
    }
  }
}

// ---------------- K5: gather + normalize -> xk (bf16 swizzled), yt (bf16 V^T tiles) ----------------
__global__ __launch_bounds__(256) void k_gather(const float* __restrict__ xe,
                                                const unsigned short* __restrict__ yeb,
                                                const int* __restrict__ sidx,
                                                unsigned short* __restrict__ xk,
                                                unsigned short* __restrict__ yt,
                                                float* __restrict__ norms) {
  int it = blockIdx.x, b = blockIdx.y;
  int i0 = it * 64;
  __shared__ float x_s[64 * 65];
  __shared__ unsigned short y_s[16 * 260];
  __shared__ int idx_s[64];
  __shared__ float scale_s[64];
  int t = threadIdx.x;
  if (t < 64) idx_s[t] = sidx[b * L + i0 + t];
  __syncthreads();
  for (int e = t; e < 4096; e += 256) {
    int i = e >> 6, d = e & 63;
    x_s[i * 65 + d] = xe[((size_t)b * L + idx_s[i]) * 64 + d];
  }
  __syncthreads();
  if (t < 64) {
    float s = 0.f;
    const float* xr = &x_s[t * 65];
#pragma unroll
    for (int d = 0; d < 64; ++d) s += xr[d] * xr[d];
    float n = fmaxf(sqrtf(s), 5e-5f);
    norms[b * L + i0 + t] = n;
    scale_s[t] = 1.0f / n;
  }
  __syncthreads();
  for (int e = t; e < 4096; e += 256) {
    int i = e >> 6, d = e & 63;
    int ig = i0 + i;
    int db = (((d >> 3) ^ (ig & 7)) << 3) | (d & 7);
    xk[((size_t)b * L + ig) * 64 + db] = (unsigned short)f2bf(x_s[i * 65 + d] * scale_s[i]);
  }
  for (int tile = 0; tile < 4; ++tile) {
    for (int e = t; e < 4096; e += 256) {
      int i16 = e >> 8, c = e & 255;
      y_s[i16 * 260 + c] = yeb[((size_t)b * L + idx_s[tile * 16 + i16]) * 256 + c];
    }
    __syncthreads();
    size_t tb = (size_t)b * L * 256 + (size_t)((i0 >> 4) + tile) * 4096;
    for (int e = t; e < 4096; e += 256) {
      int c = e >> 4, k16 = e & 15;
      int sw = ((((k16 >> 2) ^ ((c >> 2) & 3)) << 2) | (k16 & 3));
      yt[tb + c * 16 + sw] = y_s[k16 * 260 + c];
    }
    __syncthreads();
  }
}

// ---------------- K6: flash MFMA attention ----------------
// grid (512) linear: b = i&7 (XCD affinity), k = i>>3. 576 thr = 9 waves, wave w owns
// queries kbase + w*16. K/V staged ONCE per window. Defer-max THR=8.
__global__ __launch_bounds__(576, 1) void k_attn(const unsigned short* __restrict__ xk,
                                                 const unsigned short* __restrict__ yt,
                                                 const float* __restrict__ norms,
                                                 const int* __restrict__ sidx,
                                                 float* __restrict__ retb) {
  int i = blockIdx.x;
  int b = i & 7, k = i >> 3;
  __shared__ __align__(16) char lds[40960];
  int t = threadIdx.x;
  int lane = t & 63;
  int g = lane >> 4, kr = lane & 15;
  int kbase = k * WIN;
  int qr0 = kbase + (t >> 6) * 16;
  int qrow = qr0 + kr;

  s8v qf[2];
#pragma unroll
  for (int s = 0; s < 2; ++s) {
    int blk = (4 * s + g) ^ (qrow & 7);
    qf[s] = *(const s8v*)(xk + ((size_t)b * L + qrow) * 64 + blk * 8);
  }
  float qn = norms[(size_t)b * L + qrow];

  f32x4 acc[16];
#pragma unroll
  for (int nf = 0; nf < 16; ++nf) acc[nf] = (f32x4){0.f, 0.f, 0.f, 0.f};
  float runm = -3e38f, runsum = 0.f;

  auto stage = [&](int c, int buf) {
    char* kb = lds + buf * 20480;
    char* vb = kb + 4096;
    for (int e = t; e < 1280; e += 576) {
      if (e < 256) {
        int key32 = e >> 3;
        if (c == 13 && key32 >= 16) continue;
        int j = c * 32 + key32;
        int r = (j >= 288) ? 2 : (j >= 144) ? 1 : 0;
        int kk = (r == 0) ? k : (r == 1) ? ((k + 63) & 63) : ((k + 1) & 63);
        int phys = kk * WIN + (j - r * 144);
        const char* gp = (const char*)xk + (((size_t)b * L + phys) * 64 + (e & 7) * 8) * 2;
        __builtin_amdgcn_global_load_lds((const __attribute__((address_space(1))) void*)gp,
                                         (__attribute__((address_space(3))) void*)(kb + e * 16),
                                         16, 0, 0);
      } else {
        int u = e - 256;
        int f = u >> 9;
        if (c == 13 && f == 1) continue;
        int j0 = c * 32 + f * 16;
        int r = (j0 >= 288) ? 2 : (j0 >= 144) ? 1 : 0;
        int kk = (r == 0) ? k : (r == 1) ? ((k + 63) & 63) : ((k + 1) & 63);
        int rowbase = kk * WIN + (j0 - r * 144);
        const char* gp = (const char*)yt + ((size_t)b * L + rowbase) * 512 + (size_t)(u & 511) * 16;
        __builtin_amdgcn_global_load_lds((const __attribute__((address_space(1))) void*)gp,
                                         (__attribute__((address_space(3))) void*)(vb + u * 16),
                                         16, 0, 0);
      }
    }
  };

  auto compute = [&](int c, int buf) {
    char* kb = lds + buf * 20480;
    char* vb = kb + 4096;
    int nm = (c == 13) ? 1 : 2;
    f32x4 sa[2];
    sa[0] = (f32x4){0.f, 0.f, 0.f, 0.f};
    sa[1] = (f32x4){0.f, 0.f, 0.f, 0.f};
#pragma unroll
    for (int m = 0; m < 2; ++m)
      if (m < nm) {
        int row32 = m * 16 + kr;
#pragma unroll
        for (int s = 0; s < 2; ++s) {
          int off = row32 * 128 + (((4 * s + g) ^ (row32 & 7)) * 16);
          s8v kf = *(const s8v*)(kb + off);
          sa[m] = __builtin_amdgcn_mfma_f32_16x16x32_bf16(kf, qf[s], sa[m], 0, 0, 0);
        }
      }
    float p[2][4];
    float mx = -3e38f;
#pragma unroll
    for (int m = 0; m < 2; ++m)
#pragma unroll
      for (int r = 0; r < 4; ++r) {
        float v = (m < nm) ? sa[m][r] * qn : -3e38f;
        p[m][r] = v;
        mx = fmaxf(mx, v);
      }
    mx = fmaxf(mx, __shfl_xor(mx, 16));
    mx = fmaxf(mx, __shfl_xor(mx, 32));
    if (!__all(mx <= runm + 8.f)) {
      float newm = fmaxf(runm, mx);
      float corr = __expf(runm - newm);
      runm = newm;
      runsum *= corr;
      float f0 = __shfl(corr, 4 * g + 0);
      float f1 = __shfl(corr, 4 * g + 1);
      float f2 = __shfl(corr, 4 * g + 2);
      float f3 = __shfl(corr, 4 * g + 3);
#pragma unroll
      for (int nf = 0; nf < 16; ++nf) {
        acc[nf][0] *= f0; acc[nf][1] *= f1; acc[nf][2] *= f2; acc[nf][3] *= f3;
      }
    }
    float psum = 0.f;
#pragma unroll
    for (int m = 0; m < 2; ++m)
#pragma unroll
      for (int r = 0; r < 4; ++r) {
        float pv = __expf(p[m][r] - runm);
        p[m][r] = pv;
        psum += pv;
      }
    runsum += psum;
    s8v pa;
#pragma unroll
    for (int e2 = 0; e2 < 8; ++e2) pa[e2] = f2bf(p[e2 >> 2][e2 & 3]);
#pragma unroll
    for (int nf = 0; nf < 16; ++nf) {
      int cch = nf * 16 + kr;
      int grp = g ^ ((cch >> 2) & 3);
      s4v lo = *(const s4v*)(vb + cch * 32 + grp * 8);
      s4v hi = *(const s4v*)(vb + 8192 + cch * 32 + grp * 8);
      s8v bfv = __builtin_shufflevector(lo, hi, 0, 1, 2, 3, 4, 5, 6, 7);
      acc[nf] = __builtin_amdgcn_mfma_f32_16x16x32_bf16(pa, bfv, acc[nf], 0, 0, 0);
    }
  };

  stage(0, 0);
  __syncthreads();
  for (int c = 0; c < 14; ++c) {
    if (c < 13) stage(c + 1, (c + 1) & 1);
    compute(c, c & 1);
    __syncthreads();
  }

  runsum += __shfl_xor(runsum, 16);
  runsum += __shfl_xor(runsum, 32);
  float inv = 1.0f / runsum;
  float invr[4];
  int lorig[4];
#pragma unroll
  for (int r = 0; r < 4; ++r) {
    invr[r] = __shfl(inv, 4 * g + r);
    lorig[r] = sidx[b * L + qr0 + 4 * g + r];
  }
#pragma unroll
  for (int nf = 0; nf < 16; ++nf)
#pragma unroll
    for (int r = 0; r < 4; ++r)
      retb[((size_t)b * L + lorig[r]) * 256 + nf * 16 + kr] = acc[nf][r] * invr[r];
}

// ---------------- K7: transpose + residual ----------------
__global__ __launch_bounds__(256) void k_final(const float* __restrict__ in,
                                               const float* __restrict__ retb,
                                               float* __restrict__ out) {
  int lt = blockIdx.x, ct = blockIdx.y, b = blockIdx.z;
  int l0 = lt * 32, c0 = ct * 32;
  __shared__ float t_s[32][33];
  int t = threadIdx.x;
  for (int e = t; e < 1024; e += 256) {
    int i = e >> 5, j = e & 31;
    t_s[i][j] = retb[((size_t)b * L + l0 + i) * 256 + c0 + j];
  }
  __syncthreads();
  for (int e = t; e < 1024; e += 256) {
    int ci = e >> 5, lj = e & 31;
    size_t o = ((size_t)b * CC + c0 + ci) * L + l0 + lj;
    out[o] = in[o] + 0.1f * t_s[lj][ci];
  }
}

extern "C" void kernel_launch(void* const* d_in, const int* in_sizes, int n_in,
                              void* d_out, int out_size, void* d_ws, size_t ws_size,
                              hipStream_t stream) {
  const float* input = (const float*)d_in[0];
  const float* wm = (const float*)d_in[1];
  const float* bm = (const float*)d_in[2];
  const float* wa = (const float*)d_in[3];
  const float* ba = (const float*)d_in[4];
  const float* means = (const float*)d_in[5];
  float* out = (float*)d_out;

  float* ws = (float*)d_ws;
  float* x_embed = ws;                                      // 4,718,592 f
  float* y_embed = ws + 4718592ull;                         // 18,874,368 f (aliased: xhi/yeb, retb)
  float* retb = y_embed;
  unsigned short* xk = (unsigned short*)(ws + 23592960ull); // 4,718,592 bf16 (aliased: w bufs)
  unsigned short* yt = (unsigned short*)(ws + 25952256ull); // 18,874,368 bf16
  float* norms = ws + 35389440ull;                          // 73,728 f
  int* buckets = (int*)(ws + 35463168ull);                  // 73,728 i
  int* sidx = buckets + 73728;                              // 73,728 i
  unsigned short* xhi = (unsigned short*)y_embed;           // 18,874,368 bf16 (first half)
  unsigned short* xlo = xhi + 18874368ull;                  // second half; becomes yeb
  unsigned short* yeb = xlo;
  unsigned short* whiB = xk;                                // 294,912 bf16
  unsigned short* wloB = whiB + 294912ull;                  // 294,912 bf16
  unsigned short* wt1 = wloB + 294912ull;                   // 65,536 bf16
  // conv3 partial (ich=1): aliases the yt region (yt written later by k_gather)
  float* xpart = ws + 25952256ull;                          // 4,718,592 f

  k_isplit<<<dim3(96, 16, 8), 256, 0, stream>>>(input, xhi, xlo);
  k_wsplit<<<dim3(576), 256, 0, stream>>>(wm, whiB, wloB);
  k_w1prep<<<dim3(256), 256, 0, stream>>>(wa, wt1);
  k_conv3<<<dim3(768), 192, 0, stream>>>(xhi, xlo, whiB, wloB, bm, x_embed, xpart);
  k_xred<<<dim3(4608), 256, 0, stream>>>(x_embed, xpart);
  k_conv1<<<dim3(96, 8), 384, 0, stream>>>(xhi, wt1, ba, yeb);
  k_bucket<<<dim3(288, 8), 256, 0, stream>>>(x_embed, means, buckets);
  k_sort<<<dim3(8), 256, 0, stream>>>(buckets, sidx);
  k_gather<<<dim3(144, 8), 256, 0, stream>>>(x_embed, yeb, sidx, xk, yt, norms);
  k_attn<<<dim3(512), 576, 0, stream>>>(xk, yt, norms, sidx, retb);
  k_final<<<dim3(288, 8, 8), 256, 0, stream>>>(input, retb, out);
}

// Round 17
// 300.012 us; speedup vs baseline: 1.0724x; 1.0724x over previous
//
#include <hip/hip_runtime.h>
#include <math.h>

#define L 9216
#define HH 96
#define WW 96
#define CC 256
#define CR 64
#define NCLUST 128
#define WIN 144
#define NK 64   // L/WIN

typedef float f32x4 __attribute__((ext_vector_type(4)));
typedef float f32x16 __attribute__((ext_vector_type(16)));
typedef short s8v __attribute__((ext_vector_type(8)));
typedef short s4v __attribute__((ext_vector_type(4)));

static __device__ __forceinline__ short f2bf(float x) {
  union { float f; unsigned u; } v; v.f = x;
  unsigned r = (v.u + 0x7FFF + ((v.u >> 16) & 1)) >> 16;
  return (short)r;
}
static __device__ __forceinline__ float bf2f(short h) {
  union { float f; unsigned u; } v;
  v.u = ((unsigned)(unsigned short)h) << 16;
  return v.f;
}

// ---------------- K0a: input split fp32 -> xhi/xlo bf16, layout [b][h][icc16][w96][ic16] ----------------
__global__ __launch_bounds__(256) void k_isplit(const float* __restrict__ in,
                                                unsigned short* __restrict__ xhi,
                                                unsigned short* __restrict__ xlo) {
  int h = blockIdx.x, icc = blockIdx.y, b = blockIdx.z;
  __shared__ float tile[16][97];
  int t = threadIdx.x;
  for (int e = t; e < 1536; e += 256) {
    int ic = e / 96, w = e % 96;
    tile[ic][w] = in[((size_t)(b * 256 + icc * 16 + ic)) * L + h * 96 + w];
  }
  __syncthreads();
  size_t base = (((size_t)b * 96 + h) * 16 + icc) * 1536;
  for (int e = t; e < 1536; e += 256) {
    int w = e >> 4, ic = e & 15;
    float v = tile[ic][w];
    short hi = f2bf(v);
    float rv = v - bf2f(hi);
    short lo = f2bf(rv);
    xhi[base + e] = (unsigned short)hi;
    xlo[base + e] = (unsigned short)lo;
  }
}

// ---------------- K0b: conv3 weight split -> whiB/wloB [icc][tap][oc64][ic16] bf16 ----------------
__global__ __launch_bounds__(256) void k_wsplit(const float* __restrict__ wm,
                                                unsigned short* __restrict__ whiB,
                                                unsigned short* __restrict__ wloB) {
  int idx = blockIdx.x * 256 + threadIdx.x;
  if (idx < 147456) {
    int ic = idx & 15;
    int oc = (idx >> 4) & 63;
    int g = idx >> 10;
    int tap = g % 9, icc = g / 9;
    float v = wm[(size_t)oc * 2304 + (icc * 16 + ic) * 9 + tap];
    short hi = f2bf(v);
    float rv = v - bf2f(hi);
    whiB[idx] = (unsigned short)hi;
    wloB[idx] = (unsigned short)f2bf(rv);
  }
}

// ---------------- K0c: conv1 weight prep -> wt1 [icc][oc256][ic16] bf16 ----------------
__global__ __launch_bounds__(256) void k_w1prep(const float* __restrict__ wa,
                                                unsigned short* __restrict__ wt1) {
  int idx = blockIdx.x * 256 + threadIdx.x;  // 65536 total
  int ic = idx & 15, oc = (idx >> 4) & 255, icc = idx >> 12;
  wt1[idx] = (unsigned short)f2bf(wa[(size_t)oc * 256 + icc * 16 + ic]);
}

// ---------------- K1: conv3x3 via MFMA (split-bf16, 3 products) ----------------
// [RESTORED: exact R13 version, measured 80.2 us] grid 768 linear: b = i&7 (XCD
// affinity), h = i>>3. 192 thr = 3 waves; wave pt owns 32 px x 64 oc.
__global__ __launch_bounds__(192) void k_conv3(const unsigned short* __restrict__ xhi,
                                               const unsigned short* __restrict__ xlo,
                                               const unsigned short* __restrict__ whiB,
                                               const unsigned short* __restrict__ wloB,
                                               const float* __restrict__ bm,
                                               float* __restrict__ xe) {
  int i = blockIdx.x;
  int b = i & 7, h = i >> 3;
  __shared__ __align__(16) unsigned short lds[2 * 2 * 3 * 98 * 16];  // 37632 B
  int t = threadIdx.x;
  int pt = t >> 6, lane = t & 63;
  int hh = lane >> 5, j = lane & 31;
  int r = lane & 31;

  // zero the halo column slots (0 and 97) of all 2x2x3 planes
  for (int e = t; e < 384; e += 192) {
    int slot = e >> 4, ic = e & 15;
    int bs = slot / 6, rem = slot % 6;
    int rr = rem >> 1, cc = rem & 1;
    lds[bs * 4704 + rr * 1568 + (cc ? 97 : 0) * 16 + ic] = 0;
  }

  f32x16 acc0 = {}, acc1 = {};

  auto stage = [&](int icc, int buf) {
#pragma unroll
    for (int k6 = 0; k6 < 6; ++k6) {
      int u = t + k6 * 192;
      int s = u / 576;
      int rem = u - s * 576;
      int rr = rem / 192;
      int q = rem - rr * 192;
      int gr = h - 1 + rr;
      unsigned short* dst = &lds[(buf * 2 + s) * 4704 + rr * 1568 + 16 + q * 8];
      if (gr >= 0 && gr < 96) {
        const unsigned short* src =
            (s ? xlo : xhi) + ((((size_t)b * 96 + gr) * 16 + icc) * 1536 + q * 8);
        __builtin_amdgcn_global_load_lds((const __attribute__((address_space(1))) void*)src,
                                         (__attribute__((address_space(3))) void*)dst, 16, 0, 0);
      } else {
        *(s8v*)dst = (s8v){0, 0, 0, 0, 0, 0, 0, 0};
      }
    }
  };

  auto compute = [&](int icc, int buf) {
    const unsigned short* lbase = lds + buf * 9408;
    const unsigned short* wb = whiB + (size_t)icc * 9216;
    const unsigned short* wl = wloB + (size_t)icc * 9216;
#pragma unroll
    for (int kh = 0; kh < 3; ++kh)
#pragma unroll
      for (int kw = 0; kw < 3; ++kw) {
        int tap = kh * 3 + kw;
        int aidx = kh * 1568 + (pt * 32 + r + kw) * 16 + hh * 8;
        s8v a_hi = *(const s8v*)(lbase + aidx);
        s8v a_lo = *(const s8v*)(lbase + 4704 + aidx);
        int woff = tap * 1024 + j * 16 + hh * 8;
        s8v b_hi0 = *(const s8v*)(wb + woff);
        s8v b_lo0 = *(const s8v*)(wl + woff);
        s8v b_hi1 = *(const s8v*)(wb + woff + 512);
        s8v b_lo1 = *(const s8v*)(wl + woff + 512);
        acc0 = __builtin_amdgcn_mfma_f32_32x32x16_bf16(a_hi, b_hi0, acc0, 0, 0, 0);
        acc0 = __builtin_amdgcn_mfma_f32_32x32x16_bf16(a_hi, b_lo0, acc0, 0, 0, 0);
        acc0 = __builtin_amdgcn_mfma_f32_32x32x16_bf16(a_lo, b_hi0, acc0, 0, 0, 0);
        acc1 = __builtin_amdgcn_mfma_f32_32x32x16_bf16(a_hi, b_hi1, acc1, 0, 0, 0);
        acc1 = __builtin_amdgcn_mfma_f32_32x32x16_bf16(a_hi, b_lo1, acc1, 0, 0, 0);
        acc1 = __builtin_amdgcn_mfma_f32_32x32x16_bf16(a_lo, b_hi1, acc1, 0, 0, 0);
      }
  };

  stage(0, 0);
  __syncthreads();
#pragma unroll 1
  for (int icc = 0; icc < 16; ++icc) {
    int buf = icc & 1;
    if (icc < 15) stage(icc + 1, buf ^ 1);
    compute(icc, buf);
    __syncthreads();
  }

  float bv0 = bm[j], bv1 = bm[32 + j];
#pragma unroll
  for (int reg = 0; reg < 16; ++reg) {
    int prow = (reg & 3) + 8 * (reg >> 2) + 4 * hh;
    size_t rowbase = ((size_t)b * L + h * 96 + pt * 32 + prow) * 64;
    xe[rowbase + j] = acc0[reg] + bv0;
    xe[rowbase + 32 + j] = acc1[reg] + bv1;
  }
}

// ---------------- K2: conv1x1 via MFMA bf16 (no LDS, no barriers) ----------------
__global__ __launch_bounds__(384) void k_conv1(const unsigned short* __restrict__ xhi,
                                               const unsigned short* __restrict__ wt1,
                                               const float* __restrict__ ba,
                                               unsigned short* __restrict__ yeb) {
  int h = blockIdx.x, b = blockIdx.y;
  int t = threadIdx.x;
  int wave = t >> 6, lane = t & 63;
  int pt = wave % 3, ot = wave / 3;
  int hh = lane >> 5, j = lane & 31;
  int r = lane & 31;

  f32x16 acc[4] = {};
  const unsigned short* abase =
      xhi + (((size_t)b * 96 + h) * 16) * 1536 + (pt * 32 + r) * 16 + hh * 8;
  const unsigned short* bbase = wt1 + (ot * 128 + j) * 16 + hh * 8;
#pragma unroll 2
  for (int icc = 0; icc < 16; ++icc) {
    s8v av = *(const s8v*)(abase + icc * 1536);
    const unsigned short* bp = bbase + icc * 4096;
#pragma unroll
    for (int tile = 0; tile < 4; ++tile) {
      s8v bv = *(const s8v*)(bp + tile * 512);
      acc[tile] = __builtin_amdgcn_mfma_f32_32x32x16_bf16(av, bv, acc[tile], 0, 0, 0);
    }
  }
#pragma unroll
  for (int tile = 0; tile < 4; ++tile) {
    int oc = ot * 128 + tile * 32 + j;
    float bias = ba[oc];
#pragma unroll
    for (int reg = 0; reg < 16; ++reg) {
      int prow = (reg & 3) + 8 * (reg >> 2) + 4 * hh;
      yeb[((size_t)b * L + h * 96 + pt * 32 + prow) * 256 + oc] =
          (unsigned short)f2bf(acc[tile][reg] + bias);
    }
  }
}

// ---------------- K3: buckets = argmax_c(x . mean_c) ----------------
__global__ __launch_bounds__(256) void k_bucket(const float* __restrict__ xe,
                                                const float* __restrict__ means,
                                                int* __restrict__ buckets) {
  int lt = blockIdx.x, b = blockIdx.y;
  int l0 = lt * 32;
  __shared__ float x_s[32 * 65];
  __shared__ float m_s[128 * 65];
  __shared__ float bv_s[32 * 8];
  __shared__ int bi_s[32 * 8];
  int t = threadIdx.x;
  for (int e = t; e < 2048; e += 256) {
    int px = e >> 6, d = e & 63;
    x_s[px * 65 + d] = xe[((size_t)b * L + l0) * 64 + e];
  }
  for (int e = t; e < 8192; e += 256) {
    int c = e >> 6, d = e & 63;
    m_s[c * 65 + d] = means[e];
  }
  __syncthreads();
  int px = t >> 3, cg = t & 7;
  float best = -1e30f;
  int bidx = 0;
  const float* xr = &x_s[px * 65];
  for (int cc = 0; cc < 16; ++cc) {
    int c = cg + 8 * cc;
    const float* mr = &m_s[c * 65];
    float d = 0.f;
#pragma unroll
    for (int dd = 0; dd < 64; ++dd) d += xr[dd] * mr[dd];
    if (d > best || (d == best && c < bidx)) { best = d; bidx = c; }
  }
  bv_s[px * 8 + cg] = best;
  bi_s[px * 8 + cg] = bidx;
  __syncthreads();
  if (cg == 0) {
    float bb = bv_s[px * 8];
    int bbi = bi_s[px * 8];
    for (int g = 1; g < 8; ++g) {
      float v = bv_s[px * 8 + g];
      int vi = bi_s[px * 8 + g];
      if (v > bb || (v == bb && vi < bbi)) { bb = v; bbi = vi; }
    }
    buckets[b * L + l0 + px] = bbi;
  }
}

// ---------------- K4: parallel stable counting sort ----------------
#define SCH 256
#define CHL 36
__global__ __launch_bounds__(256) void k_sort(const int* __restrict__ buckets,
                                              int* __restrict__ sidx) {
  int b = blockIdx.x, t = threadIdx.x;
  __shared__ int keys_s[L];
  __shared__ unsigned short cnt_s[SCH][130];
  __shared__ int halfsum0[NCLUST];
  __shared__ int keytotal[NCLUST];
  __shared__ int keybase[NCLUST];
  const int* bk = buckets + b * L;
  for (int i = t; i < L; i += SCH) keys_s[i] = bk[i];
  for (int i = 0; i < 130; ++i) cnt_s[t][i] = 0;
  __syncthreads();
  {
    int base = t * CHL;
    for (int i = 0; i < CHL; ++i) cnt_s[t][keys_s[base + i]]++;
  }
  __syncthreads();
  {
    int kkey = t & 127, h = t >> 7;
    int c0 = h * 128;
    int run = 0;
    for (int c = 0; c < 128; ++c) {
      int v = cnt_s[c0 + c][kkey];
      cnt_s[c0 + c][kkey] = (unsigned short)run;
      run += v;
    }
    if (h == 0) halfsum0[kkey] = run;
    else keytotal[kkey] = run;
  }
  __syncthreads();
  if (t < NCLUST) keytotal[t] += halfsum0[t];
  __syncthreads();
  if (t == 0) {
    int s = 0;
    for (int i = 0; i < NCLUST; ++i) { keybase[i] = s; s += keytotal[i]; }
  }
  __syncthreads();
  {
    int h = t >> 7;
    int base = t * CHL;
    int* sb = sidx + b * L;
    for (int i = 0; i < CHL; ++i) {
      int kkey = keys_s[base + i];
      int pos = keybase[kkey] + (h ? halfsum0[kkey] : 0) + cnt_s[t][kkey];
      cnt_s[t][kkey]++;
      sb[pos] = base + i;
    }
  }
}

// ---------------- K5: gather + normalize -> xk (bf16 swizzled), yt (bf16 V^T tiles) ----------------
__global__ __launch_bounds__(256) void k_gather(const float* __restrict__ xe,
                                                const unsigned short* __restrict__ yeb,
                                                const int* __restrict__ sidx,
                                                unsigned short* __restrict__ xk,
                                                unsigned short* __restrict__ yt,
                                                float* __restrict__ norms) {
  int it = blockIdx.x, b = blockIdx.y;
  int i0 = it * 64;
  __shared__ float x_s[64 * 65];
  __shared__ unsigned short y_s[16 * 260];
  __shared__ int idx_s[64];
  __shared__ float scale_s[64];
  int t = threadIdx.x;
  if (t < 64) idx_s[t] = sidx[b * L + i0 + t];
  __syncthreads();
  for (int e = t; e < 4096; e += 256) {
    int i = e >> 6, d = e & 63;
    x_s[i * 65 + d] = xe[((size_t)b * L + idx_s[i]) * 64 + d];
  }
  __syncthreads();
  if (t < 64) {
    float s = 0.f;
    const float* xr = &x_s[t * 65];
#pragma unroll
    for (int d = 0; d < 64; ++d) s += xr[d] * xr[d];
    float n = fmaxf(sqrtf(s), 5e-5f);
    norms[b * L + i0 + t] = n;
    scale_s[t] = 1.0f / n;
  }
  __syncthreads();
  for (int e = t; e < 4096; e += 256) {
    int i = e >> 6, d = e & 63;
    int ig = i0 + i;
    int db = (((d >> 3) ^ (ig & 7)) << 3) | (d & 7);
    xk[((size_t)b * L + ig) * 64 + db] = (unsigned short)f2bf(x_s[i * 65 + d] * scale_s[i]);
  }
  for (int tile = 0; tile < 4; ++tile) {
    for (int e = t; e < 4096; e += 256) {
      int i16 = e >> 8, c = e & 255;
      y_s[i16 * 260 + c] = yeb[((size_t)b * L + idx_s[tile * 16 + i16]) * 256 + c];
    }
    __syncthreads();
    size_t tb = (size_t)b * L * 256 + (size_t)((i0 >> 4) + tile) * 4096;
    for (int e = t; e < 4096; e += 256) {
      int c = e >> 4, k16 = e & 15;
      int sw = ((((k16 >> 2) ^ ((c >> 2) & 3)) << 2) | (k16 & 3));
      yt[tb + c * 16 + sw] = y_s[k16 * 260 + c];
    }
    __syncthreads();
  }
}

// ---------------- K6: flash MFMA attention ----------------
// grid (512) linear: b = i&7 (XCD affinity), k = i>>3. 576 thr = 9 waves, wave w owns
// queries kbase + w*16. K/V staged ONCE per window. Defer-max THR=8.
__global__ __launch_bounds__(576, 1) void k_attn(const unsigned short* __restrict__ xk,
                                                 const unsigned short* __restrict__ yt,
                                                 const float* __restrict__ norms,
                                                 const int* __restrict__ sidx,
                                                 float* __restrict__ retb) {
  int i = blockIdx.x;
  int b = i & 7, k = i >> 3;
  __shared__ __align__(16) char lds[40960];
  int t = threadIdx.x;
  int lane = t & 63;
  int g = lane >> 4, kr = lane & 15;
  int kbase = k * WIN;
  int qr0 = kbase + (t >> 6) * 16;
  int qrow = qr0 + kr;

  s8v qf[2];
#pragma unroll
  for (int s = 0; s < 2; ++s) {
    int blk = (4 * s + g) ^ (qrow & 7);
    qf[s] = *(const s8v*)(xk + ((size_t)b * L + qrow) * 64 + blk * 8);
  }
  float qn = norms[(size_t)b * L + qrow];

  f32x4 acc[16];
#pragma unroll
  for (int nf = 0; nf < 16; ++nf) acc[nf] = (f32x4){0.f, 0.f, 0.f, 0.f};
  float runm = -3e38f, runsum = 0.f;

  auto stage = [&](int c, int buf) {
    char* kb = lds + buf * 20480;
    char* vb = kb + 4096;
    for (int e = t; e < 1280; e += 576) {
      if (e < 256) {
        int key32 = e >> 3;
        if (c == 13 && key32 >= 16) continue;
        int j = c * 32 + key32;
        int r = (j >= 288) ? 2 : (j >= 144) ? 1 : 0;
        int kk = (r == 0) ? k : (r == 1) ? ((k + 63) & 63) : ((k + 1) & 63);
        int phys = kk * WIN + (j - r * 144);
        const char* gp = (const char*)xk + (((size_t)b * L + phys) * 64 + (e & 7) * 8) * 2;
        __builtin_amdgcn_global_load_lds((const __attribute__((address_space(1))) void*)gp,
                                         (__attribute__((address_space(3))) void*)(kb + e * 16),
                                         16, 0, 0);
      } else {
        int u = e - 256;
        int f = u >> 9;
        if (c == 13 && f == 1) continue;
        int j0 = c * 32 + f * 16;
        int r = (j0 >= 288) ? 2 : (j0 >= 144) ? 1 : 0;
        int kk = (r == 0) ? k : (r == 1) ? ((k + 63) & 63) : ((k + 1) & 63);
        int rowbase = kk * WIN + (j0 - r * 144);
        const char* gp = (const char*)yt + ((size_t)b * L + rowbase) * 512 + (size_t)(u & 511) * 16;
        __builtin_amdgcn_global_load_lds((const __attribute__((address_space(1))) void*)gp,
                                         (__attribute__((address_space(3))) void*)(vb + u * 16),
                                         16, 0, 0);
      }
    }
  };

  auto compute = [&](int c, int buf) {
    char* kb = lds + buf * 20480;
    char* vb = kb + 4096;
    int nm = (c == 13) ? 1 : 2;
    f32x4 sa[2];
    sa[0] = (f32x4){0.f, 0.f, 0.f, 0.f};
    sa[1] = (f32x4){0.f, 0.f, 0.f, 0.f};
#pragma unroll
    for (int m = 0; m < 2; ++m)
      if (m < nm) {
        int row32 = m * 16 + kr;
#pragma unroll
        for (int s = 0; s < 2; ++s) {
          int off = row32 * 128 + (((4 * s + g) ^ (row32 & 7)) * 16);
          s8v kf = *(const s8v*)(kb + off);
          sa[m] = __builtin_amdgcn_mfma_f32_16x16x32_bf16(kf, qf[s], sa[m], 0, 0, 0);
        }
      }
    float p[2][4];
    float mx = -3e38f;
#pragma unroll
    for (int m = 0; m < 2; ++m)
#pragma unroll
      for (int r = 0; r < 4; ++r) {
        float v = (m < nm) ? sa[m][r] * qn : -3e38f;
        p[m][r] = v;
        mx = fmaxf(mx, v);
      }
    mx = fmaxf(mx, __shfl_xor(mx, 16));
    mx = fmaxf(mx, __shfl_xor(mx, 32));
    if (!__all(mx <= runm + 8.f)) {
      float newm = fmaxf(runm, mx);
      float corr = __expf(runm - newm);
      runm = newm;
      runsum *= corr;
      float f0 = __shfl(corr, 4 * g + 0);
      float f1 = __shfl(corr, 4 * g + 1);
      float f2 = __shfl(corr, 4 * g + 2);
      float f3 = __shfl(corr, 4 * g + 3);
#pragma unroll
      for (int nf = 0; nf < 16; ++nf) {
        acc[nf][0] *= f0; acc[nf][1] *= f1; acc[nf][2] *= f2; acc[nf][3] *= f3;
      }
    }
    float psum = 0.f;
#pragma unroll
    for (int m = 0; m < 2; ++m)
#pragma unroll
      for (int r = 0; r < 4; ++r) {
        float pv = __expf(p[m][r] - runm);
        p[m][r] = pv;
        psum += pv;
      }
    runsum += psum;
    s8v pa;
#pragma unroll
    for (int e2 = 0; e2 < 8; ++e2) pa[e2] = f2bf(p[e2 >> 2][e2 & 3]);
#pragma unroll
    for (int nf = 0; nf < 16; ++nf) {
      int cch = nf * 16 + kr;
      int grp = g ^ ((cch >> 2) & 3);
      s4v lo = *(const s4v*)(vb + cch * 32 + grp * 8);
      s4v hi = *(const s4v*)(vb + 8192 + cch * 32 + grp * 8);
      s8v bfv = __builtin_shufflevector(lo, hi, 0, 1, 2, 3, 4, 5, 6, 7);
      acc[nf] = __builtin_amdgcn_mfma_f32_16x16x32_bf16(pa, bfv, acc[nf], 0, 0, 0);
    }
  };

  stage(0, 0);
  __syncthreads();
  for (int c = 0; c < 14; ++c) {
    if (c < 13) stage(c + 1, (c + 1) & 1);
    compute(c, c & 1);
    __syncthreads();
  }

  runsum += __shfl_xor(runsum, 16);
  runsum += __shfl_xor(runsum, 32);
  float inv = 1.0f / runsum;
  float invr[4];
  int lorig[4];
#pragma unroll
  for (int r = 0; r < 4; ++r) {
    invr[r] = __shfl(inv, 4 * g + r);
    lorig[r] = sidx[b * L + qr0 + 4 * g + r];
  }
#pragma unroll
  for (int nf = 0; nf < 16; ++nf)
#pragma unroll
    for (int r = 0; r < 4; ++r)
      retb[((size_t)b * L + lorig[r]) * 256 + nf * 16 + kr] = acc[nf][r] * invr[r];
}

// ---------------- K7: transpose + residual ----------------
__global__ __launch_bounds__(256) void k_final(const float* __restrict__ in,
                                               const float* __restrict__ retb,
                                               float* __restrict__ out) {
  int lt = blockIdx.x, ct = blockIdx.y, b = blockIdx.z;
  int l0 = lt * 32, c0 = ct * 32;
  __shared__ float t_s[32][33];
  int t = threadIdx.x;
  for (int e = t; e < 1024; e += 256) {
    int i = e >> 5, j = e & 31;
    t_s[i][j] = retb[((size_t)b * L + l0 + i) * 256 + c0 + j];
  }
  __syncthreads();
  for (int e = t; e < 1024; e += 256) {
    int ci = e >> 5, lj = e & 31;
    size_t o = ((size_t)b * CC + c0 + ci) * L + l0 + lj;
    out[o] = in[o] + 0.1f * t_s[lj][ci];
  }
}

extern "C" void kernel_launch(void* const* d_in, const int* in_sizes, int n_in,
                              void* d_out, int out_size, void* d_ws, size_t ws_size,
                              hipStream_t stream) {
  const float* input = (const float*)d_in[0];
  const float* wm = (const float*)d_in[1];
  const float* bm = (const float*)d_in[2];
  const float* wa = (const float*)d_in[3];
  const float* ba = (const float*)d_in[4];
  const float* means = (const float*)d_in[5];
  float* out = (float*)d_out;

  float* ws = (float*)d_ws;
  float* x_embed = ws;                                      // 4,718,592 f
  float* y_embed = ws + 4718592ull;                         // 18,874,368 f (aliased: xhi/yeb, retb)
  float* retb = y_embed;
  unsigned short* xk = (unsigned short*)(ws + 23592960ull); // 4,718,592 bf16 (aliased: w bufs)
  unsigned short* yt = (unsigned short*)(ws + 25952256ull); // 18,874,368 bf16
  float* norms = ws + 35389440ull;                          // 73,728 f
  int* buckets = (int*)(ws + 35463168ull);                  // 73,728 i
  int* sidx = buckets + 73728;                              // 73,728 i
  unsigned short* xhi = (unsigned short*)y_embed;           // 18,874,368 bf16 (first half)
  unsigned short* xlo = xhi + 18874368ull;                  // second half; becomes yeb
  unsigned short* yeb = xlo;
  unsigned short* whiB = xk;                                // 294,912 bf16
  unsigned short* wloB = whiB + 294912ull;                  // 294,912 bf16
  unsigned short* wt1 = wloB + 294912ull;                   // 65,536 bf16

  k_isplit<<<dim3(96, 16, 8), 256, 0, stream>>>(input, xhi, xlo);
  k_wsplit<<<dim3(576), 256, 0, stream>>>(wm, whiB, wloB);
  k_w1prep<<<dim3(256), 256, 0, stream>>>(wa, wt1);
  k_conv3<<<dim3(768), 192, 0, stream>>>(xhi, xlo, whiB, wloB, bm, x_embed);
  k_conv1<<<dim3(96, 8), 384, 0, stream>>>(xhi, wt1, ba, yeb);
  k_bucket<<<dim3(288, 8), 256, 0, stream>>>(x_embed, means, buckets);
  k_sort<<<dim3(8), 256, 0, stream>>>(buckets, sidx);
  k_gather<<<dim3(144, 8), 256, 0, stream>>>(x_embed, yeb, sidx, xk, yt, norms);
  k_attn<<<dim3(512), 576, 0, stream>>>(xk, yt, norms, sidx, retb);
  k_final<<<dim3(288, 8, 8), 256, 0, stream>>>(input, retb, out);
}

// Round 18
// 280.251 us; speedup vs baseline: 1.1481x; 1.0705x over previous
//
#include <hip/hip_runtime.h>
#include <math.h>

#define L 9216
#define HH 96
#define WW 96
#define CC 256
#define CR 64
#define NCLUST 128
#define WIN 144
#define NK 64   // L/WIN

typedef float f32x4 __attribute__((ext_vector_type(4)));
typedef float f32x16 __attribute__((ext_vector_type(16)));
typedef short s8v __attribute__((ext_vector_type(8)));
typedef short s4v __attribute__((ext_vector_type(4)));

static __device__ __forceinline__ short f2bf(float x) {
  union { float f; unsigned u; } v; v.f = x;
  unsigned r = (v.u + 0x7FFF + ((v.u >> 16) & 1)) >> 16;
  return (short)r;
}
static __device__ __forceinline__ float bf2f(short h) {
  union { float f; unsigned u; } v;
  v.u = ((unsigned)(unsigned short)h) << 16;
  return v.f;
}

// ---------------- K0a: input split fp32 -> xhi/xlo bf16, layout [b][h][icc16][w96][ic16] ----------------
__global__ __launch_bounds__(256) void k_isplit(const float* __restrict__ in,
                                                unsigned short* __restrict__ xhi,
                                                unsigned short* __restrict__ xlo) {
  int h = blockIdx.x, icc = blockIdx.y, b = blockIdx.z;
  __shared__ float tile[16][97];
  int t = threadIdx.x;
  for (int e = t; e < 1536; e += 256) {
    int ic = e / 96, w = e % 96;
    tile[ic][w] = in[((size_t)(b * 256 + icc * 16 + ic)) * L + h * 96 + w];
  }
  __syncthreads();
  size_t base = (((size_t)b * 96 + h) * 16 + icc) * 1536;
  for (int e = t; e < 1536; e += 256) {
    int w = e >> 4, ic = e & 15;
    float v = tile[ic][w];
    short hi = f2bf(v);
    float rv = v - bf2f(hi);
    short lo = f2bf(rv);
    xhi[base + e] = (unsigned short)hi;
    xlo[base + e] = (unsigned short)lo;
  }
}

// ---------------- K0b: conv3 weight split -> whiB/wloB [icc][tap][oc64][ic16] bf16 ----------------
__global__ __launch_bounds__(256) void k_wsplit(const float* __restrict__ wm,
                                                unsigned short* __restrict__ whiB,
                                                unsigned short* __restrict__ wloB) {
  int idx = blockIdx.x * 256 + threadIdx.x;
  if (idx < 147456) {
    int ic = idx & 15;
    int oc = (idx >> 4) & 63;
    int g = idx >> 10;
    int tap = g % 9, icc = g / 9;
    float v = wm[(size_t)oc * 2304 + (icc * 16 + ic) * 9 + tap];
    short hi = f2bf(v);
    float rv = v - bf2f(hi);
    whiB[idx] = (unsigned short)hi;
    wloB[idx] = (unsigned short)f2bf(rv);
  }
}

// ---------------- K0c: conv1 weight prep -> wt1 [icc][oc256][ic16] bf16 ----------------
__global__ __launch_bounds__(256) void k_w1prep(const float* __restrict__ wa,
                                                unsigned short* __restrict__ wt1) {
  int idx = blockIdx.x * 256 + threadIdx.x;  // 65536 total
  int ic = idx & 15, oc = (idx >> 4) & 255, icc = idx >> 12;
  wt1[idx] = (unsigned short)f2bf(wa[(size_t)oc * 256 + icc * 16 + ic]);
}

// ---------------- K0d: means split -> mh/ml [c128][d64] bf16 ----------------
__global__ __launch_bounds__(256) void k_mprep(const float* __restrict__ means,
                                               unsigned short* __restrict__ mh,
                                               unsigned short* __restrict__ ml) {
  int idx = blockIdx.x * 256 + threadIdx.x;  // 8192 total
  if (idx < 8192) {
    float v = means[idx];
    short hi = f2bf(v);
    mh[idx] = (unsigned short)hi;
    ml[idx] = (unsigned short)f2bf(v - bf2f(hi));
  }
}

// ---------------- K1: conv3x3 via MFMA (split-bf16, 3 products) ----------------
// [R13 version, measured 80.2 us] grid 768 linear: b = i&7 (XCD affinity), h = i>>3.
// 192 thr = 3 waves; wave pt owns 32 px x 64 oc.
__global__ __launch_bounds__(192) void k_conv3(const unsigned short* __restrict__ xhi,
                                               const unsigned short* __restrict__ xlo,
                                               const unsigned short* __restrict__ whiB,
                                               const unsigned short* __restrict__ wloB,
                                               const float* __restrict__ bm,
                                               float* __restrict__ xe) {
  int i = blockIdx.x;
  int b = i & 7, h = i >> 3;
  __shared__ __align__(16) unsigned short lds[2 * 2 * 3 * 98 * 16];  // 37632 B
  int t = threadIdx.x;
  int pt = t >> 6, lane = t & 63;
  int hh = lane >> 5, j = lane & 31;
  int r = lane & 31;

  for (int e = t; e < 384; e += 192) {
    int slot = e >> 4, ic = e & 15;
    int bs = slot / 6, rem = slot % 6;
    int rr = rem >> 1, cc = rem & 1;
    lds[bs * 4704 + rr * 1568 + (cc ? 97 : 0) * 16 + ic] = 0;
  }

  f32x16 acc0 = {}, acc1 = {};

  auto stage = [&](int icc, int buf) {
#pragma unroll
    for (int k6 = 0; k6 < 6; ++k6) {
      int u = t + k6 * 192;
      int s = u / 576;
      int rem = u - s * 576;
      int rr = rem / 192;
      int q = rem - rr * 192;
      int gr = h - 1 + rr;
      unsigned short* dst = &lds[(buf * 2 + s) * 4704 + rr * 1568 + 16 + q * 8];
      if (gr >= 0 && gr < 96) {
        const unsigned short* src =
            (s ? xlo : xhi) + ((((size_t)b * 96 + gr) * 16 + icc) * 1536 + q * 8);
        __builtin_amdgcn_global_load_lds((const __attribute__((address_space(1))) void*)src,
                                         (__attribute__((address_space(3))) void*)dst, 16, 0, 0);
      } else {
        *(s8v*)dst = (s8v){0, 0, 0, 0, 0, 0, 0, 0};
      }
    }
  };

  auto compute = [&](int icc, int buf) {
    const unsigned short* lbase = lds + buf * 9408;
    const unsigned short* wb = whiB + (size_t)icc * 9216;
    const unsigned short* wl = wloB + (size_t)icc * 9216;
#pragma unroll
    for (int kh = 0; kh < 3; ++kh)
#pragma unroll
      for (int kw = 0; kw < 3; ++kw) {
        int tap = kh * 3 + kw;
        int aidx = kh * 1568 + (pt * 32 + r + kw) * 16 + hh * 8;
        s8v a_hi = *(const s8v*)(lbase + aidx);
        s8v a_lo = *(const s8v*)(lbase + 4704 + aidx);
        int woff = tap * 1024 + j * 16 + hh * 8;
        s8v b_hi0 = *(const s8v*)(wb + woff);
        s8v b_lo0 = *(const s8v*)(wl + woff);
        s8v b_hi1 = *(const s8v*)(wb + woff + 512);
        s8v b_lo1 = *(const s8v*)(wl + woff + 512);
        acc0 = __builtin_amdgcn_mfma_f32_32x32x16_bf16(a_hi, b_hi0, acc0, 0, 0, 0);
        acc0 = __builtin_amdgcn_mfma_f32_32x32x16_bf16(a_hi, b_lo0, acc0, 0, 0, 0);
        acc0 = __builtin_amdgcn_mfma_f32_32x32x16_bf16(a_lo, b_hi0, acc0, 0, 0, 0);
        acc1 = __builtin_amdgcn_mfma_f32_32x32x16_bf16(a_hi, b_hi1, acc1, 0, 0, 0);
        acc1 = __builtin_amdgcn_mfma_f32_32x32x16_bf16(a_hi, b_lo1, acc1, 0, 0, 0);
        acc1 = __builtin_amdgcn_mfma_f32_32x32x16_bf16(a_lo, b_hi1, acc1, 0, 0, 0);
      }
  };

  stage(0, 0);
  __syncthreads();
#pragma unroll 1
  for (int icc = 0; icc < 16; ++icc) {
    int buf = icc & 1;
    if (icc < 15) stage(icc + 1, buf ^ 1);
    compute(icc, buf);
    __syncthreads();
  }

  float bv0 = bm[j], bv1 = bm[32 + j];
#pragma unroll
  for (int reg = 0; reg < 16; ++reg) {
    int prow = (reg & 3) + 8 * (reg >> 2) + 4 * hh;
    size_t rowbase = ((size_t)b * L + h * 96 + pt * 32 + prow) * 64;
    xe[rowbase + j] = acc0[reg] + bv0;
    xe[rowbase + 32 + j] = acc1[reg] + bv1;
  }
}

// ---------------- K2: conv1x1 via MFMA bf16 (no LDS, no barriers) ----------------
__global__ __launch_bounds__(384) void k_conv1(const unsigned short* __restrict__ xhi,
                                               const unsigned short* __restrict__ wt1,
                                               const float* __restrict__ ba,
                                               unsigned short* __restrict__ yeb) {
  int h = blockIdx.x, b = blockIdx.y;
  int t = threadIdx.x;
  int wave = t >> 6, lane = t & 63;
  int pt = wave % 3, ot = wave / 3;
  int hh = lane >> 5, j = lane & 31;
  int r = lane & 31;

  f32x16 acc[4] = {};
  const unsigned short* abase =
      xhi + (((size_t)b * 96 + h) * 16) * 1536 + (pt * 32 + r) * 16 + hh * 8;
  const unsigned short* bbase = wt1 + (ot * 128 + j) * 16 + hh * 8;
#pragma unroll 2
  for (int icc = 0; icc < 16; ++icc) {
    s8v av = *(const s8v*)(abase + icc * 1536);
    const unsigned short* bp = bbase + icc * 4096;
#pragma unroll
    for (int tile = 0; tile < 4; ++tile) {
      s8v bv = *(const s8v*)(bp + tile * 512);
      acc[tile] = __builtin_amdgcn_mfma_f32_32x32x16_bf16(av, bv, acc[tile], 0, 0, 0);
    }
  }
#pragma unroll
  for (int tile = 0; tile < 4; ++tile) {
    int oc = ot * 128 + tile * 32 + j;
    float bias = ba[oc];
#pragma unroll
    for (int reg = 0; reg < 16; ++reg) {
      int prow = (reg & 3) + 8 * (reg >> 2) + 4 * hh;
      yeb[((size_t)b * L + h * 96 + pt * 32 + prow) * 256 + oc] =
          (unsigned short)f2bf(acc[tile][reg] + bias);
    }
  }
}

// ---------------- K3: buckets via MFMA (split-bf16, 3 products) + shfl argmax ----------------
// grid 768 linear: b = i&7, h = i>>3. 192 thr = 3 waves; wave pt owns 32 px x 128 clusters.
// A = xe rows split in-register (no LDS); B = mh/ml streamed from L2 (32 KB total).
__global__ __launch_bounds__(192) void k_bucket(const float* __restrict__ xe,
                                                const unsigned short* __restrict__ mh,
                                                const unsigned short* __restrict__ ml,
                                                int* __restrict__ buckets) {
  int i = blockIdx.x;
  int b = i & 7, h = i >> 3;
  int t = threadIdx.x;
  int pt = t >> 6, lane = t & 63;
  int hh = lane >> 5, j = lane & 31;
  int r = lane & 31;

  // A fragments: this lane's pixel row, k = kc*16 + hh*8 + e
  s8v ah[4], al[4];
  const float* xrow = xe + ((size_t)b * L + h * 96 + pt * 32 + r) * 64 + hh * 8;
#pragma unroll
  for (int kc = 0; kc < 4; ++kc) {
    f32x4 v0 = *(const f32x4*)(xrow + kc * 16);
    f32x4 v1 = *(const f32x4*)(xrow + kc * 16 + 4);
#pragma unroll
    for (int e = 0; e < 4; ++e) {
      float x0 = v0[e];
      short h0 = f2bf(x0);
      ah[kc][e] = h0;
      al[kc][e] = f2bf(x0 - bf2f(h0));
      float x1 = v1[e];
      short h1 = f2bf(x1);
      ah[kc][e + 4] = h1;
      al[kc][e + 4] = f2bf(x1 - bf2f(h1));
    }
  }

  f32x16 acc[4] = {};
#pragma unroll
  for (int kc = 0; kc < 4; ++kc) {
#pragma unroll
    for (int ct = 0; ct < 4; ++ct) {
      const unsigned short* mp = mh + (size_t)(ct * 32 + j) * 64 + kc * 16 + hh * 8;
      const unsigned short* lp = ml + (size_t)(ct * 32 + j) * 64 + kc * 16 + hh * 8;
      s8v bh = *(const s8v*)mp;
      s8v bl = *(const s8v*)lp;
      acc[ct] = __builtin_amdgcn_mfma_f32_32x32x16_bf16(ah[kc], bh, acc[ct], 0, 0, 0);
      acc[ct] = __builtin_amdgcn_mfma_f32_32x32x16_bf16(ah[kc], bl, acc[ct], 0, 0, 0);
      acc[ct] = __builtin_amdgcn_mfma_f32_32x32x16_bf16(al[kc], bh, acc[ct], 0, 0, 0);
    }
  }

  // argmax over c (32 lanes x 4 tiles) per output row; tie-break: smallest c
  int* bb = buckets + b * L + h * 96 + pt * 32;
#pragma unroll
  for (int reg = 0; reg < 16; ++reg) {
    float best = acc[0][reg];
    int bc = j;
#pragma unroll
    for (int ct = 1; ct < 4; ++ct) {
      float v = acc[ct][reg];
      int c = ct * 32 + j;
      if (v > best || (v == best && c < bc)) { best = v; bc = c; }
    }
#pragma unroll
    for (int m = 1; m <= 16; m <<= 1) {
      float ov = __shfl_xor(best, m);
      int oc = __shfl_xor(bc, m);
      if (ov > best || (ov == best && oc < bc)) { best = ov; bc = oc; }
    }
    if (j == 0) {
      int prow = (reg & 3) + 8 * (reg >> 2) + 4 * hh;
      bb[prow] = bc;
    }
  }
}

// ---------------- K4: parallel stable counting sort ----------------
#define SCH 256
#define CHL 36
__global__ __launch_bounds__(256) void k_sort(const int* __restrict__ buckets,
                                              int* __restrict__ sidx) {
  int b = blockIdx.x, t = threadIdx.x;
  __shared__ int keys_s[L];
  __shared__ unsigned short cnt_s[SCH][130];
  __shared__ int halfsum0[NCLUST];
  __shared__ int keytotal[NCLUST];
  __shared__ int keybase[NCLUST];
  const int* bk = buckets + b * L;
  for (int i = t; i < L; i += SCH) keys_s[i] = bk[i];
  for (int i = 0; i < 130; ++i) cnt_s[t][i] = 0;
  __syncthreads();
  {
    int base = t * CHL;
    for (int i = 0; i < CHL; ++i) cnt_s[t][keys_s[base + i]]++;
  }
  __syncthreads();
  {
    int kkey = t & 127, h = t >> 7;
    int c0 = h * 128;
    int run = 0;
    for (int c = 0; c < 128; ++c) {
      int v = cnt_s[c0 + c][kkey];
      cnt_s[c0 + c][kkey] = (unsigned short)run;
      run += v;
    }
    if (h == 0) halfsum0[kkey] = run;
    else keytotal[kkey] = run;
  }
  __syncthreads();
  if (t < NCLUST) keytotal[t] += halfsum0[t];
  __syncthreads();
  if (t == 0) {
    int s = 0;
    for (int i = 0; i < NCLUST; ++i) { keybase[i] = s; s += keytotal[i]; }
  }
  __syncthreads();
  {
    int h = t >> 7;
    int base = t * CHL;
    int* sb = sidx + b * L;
    for (int i = 0; i < CHL; ++i) {
      int kkey = keys_s[base + i];
      int pos = keybase[kkey] + (h ? halfsum0[kkey] : 0) + cnt_s[t][kkey];
      cnt_s[t][kkey]++;
      sb[pos] = base + i;
    }
  }
}

// ---------------- K5: gather + normalize -> xk (bf16 swizzled), yt (bf16 V^T tiles) ----------------
__global__ __launch_bounds__(256) void k_gather(const float* __restrict__ xe,
                                                const unsigned short* __restrict__ yeb,
                                                const int* __restrict__ sidx,
                                                unsigned short* __restrict__ xk,
                                                unsigned short* __restrict__ yt,
                                                float* __restrict__ norms) {
  int it = blockIdx.x, b = blockIdx.y;
  int i0 = it * 64;
  __shared__ float x_s[64 * 65];
  __shared__ unsigned short y_s[16 * 260];
  __shared__ int idx_s[64];
  __shared__ float scale_s[64];
  int t = threadIdx.x;
  if (t < 64) idx_s[t] = sidx[b * L + i0 + t];
  __syncthreads();
  for (int e = t; e < 4096; e += 256) {
    int i = e >> 6, d = e & 63;
    x_s[i * 65 + d] = xe[((size_t)b * L + idx_s[i]) * 64 + d];
  }
  __syncthreads();
  if (t < 64) {
    float s = 0.f;
    const float* xr = &x_s[t * 65];
#pragma unroll
    for (int d = 0; d < 64; ++d) s += xr[d] * xr[d];
    float n = fmaxf(sqrtf(s), 5e-5f);
    norms[b * L + i0 + t] = n;
    scale_s[t] = 1.0f / n;
  }
  __syncthreads();
  for (int e = t; e < 4096; e += 256) {
    int i = e >> 6, d = e & 63;
    int ig = i0 + i;
    int db = (((d >> 3) ^ (ig & 7)) << 3) | (d & 7);
    xk[((size_t)b * L + ig) * 64 + db] = (unsigned short)f2bf(x_s[i * 65 + d] * scale_s[i]);
  }
  for (int tile = 0; tile < 4; ++tile) {
    for (int e = t; e < 4096; e += 256) {
      int i16 = e >> 8, c = e & 255;
      y_s[i16 * 260 + c] = yeb[((size_t)b * L + idx_s[tile * 16 + i16]) * 256 + c];
    }
    __syncthreads();
    size_t tb = (size_t)b * L * 256 + (size_t)((i0 >> 4) + tile) * 4096;
    for (int e = t; e < 4096; e += 256) {
      int c = e >> 4, k16 = e & 15;
      int sw = ((((k16 >> 2) ^ ((c >> 2) & 3)) << 2) | (k16 & 3));
      yt[tb + c * 16 + sw] = y_s[k16 * 260 + c];
    }
    __syncthreads();
  }
}

// ---------------- K6: flash MFMA attention ----------------
// grid (512) linear: b = i&7 (XCD affinity), k = i>>3. 576 thr = 9 waves, wave w owns
// queries kbase + w*16. K/V staged ONCE per window. Defer-max THR=8.
__global__ __launch_bounds__(576, 1) void k_attn(const unsigned short* __restrict__ xk,
                                                 const unsigned short* __restrict__ yt,
                                                 const float* __restrict__ norms,
                                                 const int* __restrict__ sidx,
                                                 float* __restrict__ retb) {
  int i = blockIdx.x;
  int b = i & 7, k = i >> 3;
  __shared__ __align__(16) char lds[40960];
  int t = threadIdx.x;
  int lane = t & 63;
  int g = lane >> 4, kr = lane & 15;
  int kbase = k * WIN;
  int qr0 = kbase + (t >> 6) * 16;
  int qrow = qr0 + kr;

  s8v qf[2];
#pragma unroll
  for (int s = 0; s < 2; ++s) {
    int blk = (4 * s + g) ^ (qrow & 7);
    qf[s] = *(const s8v*)(xk + ((size_t)b * L + qrow) * 64 + blk * 8);
  }
  float qn = norms[(size_t)b * L + qrow];

  f32x4 acc[16];
#pragma unroll
  for (int nf = 0; nf < 16; ++nf) acc[nf] = (f32x4){0.f, 0.f, 0.f, 0.f};
  float runm = -3e38f, runsum = 0.f;

  auto stage = [&](int c, int buf) {
    char* kb = lds + buf * 20480;
    char* vb = kb + 4096;
    for (int e = t; e < 1280; e += 576) {
      if (e < 256) {
        int key32 = e >> 3;
        if (c == 13 && key32 >= 16) continue;
        int j = c * 32 + key32;
        int r = (j >= 288) ? 2 : (j >= 144) ? 1 : 0;
        int kk = (r == 0) ? k : (r == 1) ? ((k + 63) & 63) : ((k + 1) & 63);
        int phys = kk * WIN + (j - r * 144);
        const char* gp = (const char*)xk + (((size_t)b * L + phys) * 64 + (e & 7) * 8) * 2;
        __builtin_amdgcn_global_load_lds((const __attribute__((address_space(1))) void*)gp,
                                         (__attribute__((address_space(3))) void*)(kb + e * 16),
                                         16, 0, 0);
      } else {
        int u = e - 256;
        int f = u >> 9;
        if (c == 13 && f == 1) continue;
        int j0 = c * 32 + f * 16;
        int r = (j0 >= 288) ? 2 : (j0 >= 144) ? 1 : 0;
        int kk = (r == 0) ? k : (r == 1) ? ((k + 63) & 63) : ((k + 1) & 63);
        int rowbase = kk * WIN + (j0 - r * 144);
        const char* gp = (const char*)yt + ((size_t)b * L + rowbase) * 512 + (size_t)(u & 511) * 16;
        __builtin_amdgcn_global_load_lds((const __attribute__((address_space(1))) void*)gp,
                                         (__attribute__((address_space(3))) void*)(vb + u * 16),
                                         16, 0, 0);
      }
    }
  };

  auto compute = [&](int c, int buf) {
    char* kb = lds + buf * 20480;
    char* vb = kb + 4096;
    int nm = (c == 13) ? 1 : 2;
    f32x4 sa[2];
    sa[0] = (f32x4){0.f, 0.f, 0.f, 0.f};
    sa[1] = (f32x4){0.f, 0.f, 0.f, 0.f};
#pragma unroll
    for (int m = 0; m < 2; ++m)
      if (m < nm) {
        int row32 = m * 16 + kr;
#pragma unroll
        for (int s = 0; s < 2; ++s) {
          int off = row32 * 128 + (((4 * s + g) ^ (row32 & 7)) * 16);
          s8v kf = *(const s8v*)(kb + off);
          sa[m] = __builtin_amdgcn_mfma_f32_16x16x32_bf16(kf, qf[s], sa[m], 0, 0, 0);
        }
      }
    float p[2][4];
    float mx = -3e38f;
#pragma unroll
    for (int m = 0; m < 2; ++m)
#pragma unroll
      for (int r = 0; r < 4; ++r) {
        float v = (m < nm) ? sa[m][r] * qn : -3e38f;
        p[m][r] = v;
        mx = fmaxf(mx, v);
      }
    mx = fmaxf(mx, __shfl_xor(mx, 16));
    mx = fmaxf(mx, __shfl_xor(mx, 32));
    if (!__all(mx <= runm + 8.f)) {
      float newm = fmaxf(runm, mx);
      float corr = __expf(runm - newm);
      runm = newm;
      runsum *= corr;
      float f0 = __shfl(corr, 4 * g + 0);
      float f1 = __shfl(corr, 4 * g + 1);
      float f2 = __shfl(corr, 4 * g + 2);
      float f3 = __shfl(corr, 4 * g + 3);
#pragma unroll
      for (int nf = 0; nf < 16; ++nf) {
        acc[nf][0] *= f0; acc[nf][1] *= f1; acc[nf][2] *= f2; acc[nf][3] *= f3;
      }
    }
    float psum = 0.f;
#pragma unroll
    for (int m = 0; m < 2; ++m)
#pragma unroll
      for (int r = 0; r < 4; ++r) {
        float pv = __expf(p[m][r] - runm);
        p[m][r] = pv;
        psum += pv;
      }
    runsum += psum;
    s8v pa;
#pragma unroll
    for (int e2 = 0; e2 < 8; ++e2) pa[e2] = f2bf(p[e2 >> 2][e2 & 3]);
#pragma unroll
    for (int nf = 0; nf < 16; ++nf) {
      int cch = nf * 16 + kr;
      int grp = g ^ ((cch >> 2) & 3);
      s4v lo = *(const s4v*)(vb + cch * 32 + grp * 8);
      s4v hi = *(const s4v*)(vb + 8192 + cch * 32 + grp * 8);
      s8v bfv = __builtin_shufflevector(lo, hi, 0, 1, 2, 3, 4, 5, 6, 7);
      acc[nf] = __builtin_amdgcn_mfma_f32_16x16x32_bf16(pa, bfv, acc[nf], 0, 0, 0);
    }
  };

  stage(0, 0);
  __syncthreads();
  for (int c = 0; c < 14; ++c) {
    if (c < 13) stage(c + 1, (c + 1) & 1);
    compute(c, c & 1);
    __syncthreads();
  }

  runsum += __shfl_xor(runsum, 16);
  runsum += __shfl_xor(runsum, 32);
  float inv = 1.0f / runsum;
  float invr[4];
  int lorig[4];
#pragma unroll
  for (int r = 0; r < 4; ++r) {
    invr[r] = __shfl(inv, 4 * g + r);
    lorig[r] = sidx[b * L + qr0 + 4 * g + r];
  }
#pragma unroll
  for (int nf = 0; nf < 16; ++nf)
#pragma unroll
    for (int r = 0; r < 4; ++r)
      retb[((size_t)b * L + lorig[r]) * 256 + nf * 16 + kr] = acc[nf][r] * invr[r];
}

// ---------------- K7: transpose + residual ----------------
__global__ __launch_bounds__(256) void k_final(const float* __restrict__ in,
                                               const float* __restrict__ retb,
                                               float* __restrict__ out) {
  int lt = blockIdx.x, ct = blockIdx.y, b = blockIdx.z;
  int l0 = lt * 32, c0 = ct * 32;
  __shared__ float t_s[32][33];
  int t = threadIdx.x;
  for (int e = t; e < 1024; e += 256) {
    int i = e >> 5, j = e & 31;
    t_s[i][j] = retb[((size_t)b * L + l0 + i) * 256 + c0 + j];
  }
  __syncthreads();
  for (int e = t; e < 1024; e += 256) {
    int ci = e >> 5, lj = e & 31;
    size_t o = ((size_t)b * CC + c0 + ci) * L + l0 + lj;
    out[o] = in[o] + 0.1f * t_s[lj][ci];
  }
}

extern "C" void kernel_launch(void* const* d_in, const int* in_sizes, int n_in,
                              void* d_out, int out_size, void* d_ws, size_t ws_size,
                              hipStream_t stream) {
  const float* input = (const float*)d_in[0];
  const float* wm = (const float*)d_in[1];
  const float* bm = (const float*)d_in[2];
  const float* wa = (const float*)d_in[3];
  const float* ba = (const float*)d_in[4];
  const float* means = (const float*)d_in[5];
  float* out = (float*)d_out;

  float* ws = (float*)d_ws;
  float* x_embed = ws;                                      // 4,718,592 f
  float* y_embed = ws + 4718592ull;                         // 18,874,368 f (aliased: xhi/yeb, retb)
  float* retb = y_embed;
  unsigned short* xk = (unsigned short*)(ws + 23592960ull); // 4,718,592 bf16 (aliased: w bufs)
  unsigned short* yt = (unsigned short*)(ws + 25952256ull); // 18,874,368 bf16
  float* norms = ws + 35389440ull;                          // 73,728 f
  int* buckets = (int*)(ws + 35463168ull);                  // 73,728 i
  int* sidx = buckets + 73728;                              // 73,728 i
  unsigned short* xhi = (unsigned short*)y_embed;           // 18,874,368 bf16 (first half)
  unsigned short* xlo = xhi + 18874368ull;                  // second half; becomes yeb
  unsigned short* yeb = xlo;
  unsigned short* whiB = xk;                                // 294,912 bf16
  unsigned short* wloB = whiB + 294912ull;                  // 294,912 bf16
  unsigned short* wt1 = wloB + 294912ull;                   // 65,536 bf16
  unsigned short* mh = wt1 + 65536ull;                      // 8,192 bf16 (consumed before k_gather writes xk)
  unsigned short* mlp = mh + 8192ull;                       // 8,192 bf16

  k_isplit<<<dim3(96, 16, 8), 256, 0, stream>>>(input, xhi, xlo);
  k_wsplit<<<dim3(576), 256, 0, stream>>>(wm, whiB, wloB);
  k_w1prep<<<dim3(256), 256, 0, stream>>>(wa, wt1);
  k_mprep<<<dim3(32), 256, 0, stream>>>(means, mh, mlp);
  k_conv3<<<dim3(768), 192, 0, stream>>>(xhi, xlo, whiB, wloB, bm, x_embed);
  k_conv1<<<dim3(96, 8), 384, 0, stream>>>(xhi, wt1, ba, yeb);
  k_bucket<<<dim3(768), 192, 0, stream>>>(x_embed, mh, mlp, buckets);
  k_sort<<<dim3(8), 256, 0, stream>>>(buckets, sidx);
  k_gather<<<dim3(144, 8), 256, 0, stream>>>(x_embed, yeb, sidx, xk, yt, norms);
  k_attn<<<dim3(512), 576, 0, stream>>>(xk, yt, norms, sidx, retb);
  k_final<<<dim3(288, 8, 8), 256, 0, stream>>>(input, retb, out);
}

// Round 19
// 269.952 us; speedup vs baseline: 1.1919x; 1.0382x over previous
//
#include <hip/hip_runtime.h>
#include <math.h>

#define L 9216
#define HH 96
#define WW 96
#define CC 256
#define CR 64
#define NCLUST 128
#define WIN 144
#define NK 64   // L/WIN

typedef float f32x4 __attribute__((ext_vector_type(4)));
typedef float f32x16 __attribute__((ext_vector_type(16)));
typedef short s8v __attribute__((ext_vector_type(8)));
typedef short s4v __attribute__((ext_vector_type(4)));

static __device__ __forceinline__ short f2bf(float x) {
  union { float f; unsigned u; } v; v.f = x;
  unsigned r = (v.u + 0x7FFF + ((v.u >> 16) & 1)) >> 16;
  return (short)r;
}
static __device__ __forceinline__ float bf2f(short h) {
  union { float f; unsigned u; } v;
  v.u = ((unsigned)(unsigned short)h) << 16;
  return v.f;
}

// ---------------- K0a: input split fp32 -> xhi/xlo bf16, layout [b][h][icc16][w96][ic16] ----------------
__global__ __launch_bounds__(256) void k_isplit(const float* __restrict__ in,
                                                unsigned short* __restrict__ xhi,
                                                unsigned short* __restrict__ xlo) {
  int h = blockIdx.x, icc = blockIdx.y, b = blockIdx.z;
  __shared__ float tile[16][97];
  int t = threadIdx.x;
  for (int e = t; e < 1536; e += 256) {
    int ic = e / 96, w = e % 96;
    tile[ic][w] = in[((size_t)(b * 256 + icc * 16 + ic)) * L + h * 96 + w];
  }
  __syncthreads();
  size_t base = (((size_t)b * 96 + h) * 16 + icc) * 1536;
  for (int e = t; e < 1536; e += 256) {
    int w = e >> 4, ic = e & 15;
    float v = tile[ic][w];
    short hi = f2bf(v);
    float rv = v - bf2f(hi);
    short lo = f2bf(rv);
    xhi[base + e] = (unsigned short)hi;
    xlo[base + e] = (unsigned short)lo;
  }
}

// ---------------- K0b: merged weight/means prep ----------------
// blocks [0,576): conv3 wsplit; [576,832): conv1 w1prep; [832,864): means mprep
__global__ __launch_bounds__(256) void k_prep(const float* __restrict__ wm,
                                              const float* __restrict__ wa,
                                              const float* __restrict__ means,
                                              unsigned short* __restrict__ whiB,
                                              unsigned short* __restrict__ wloB,
                                              unsigned short* __restrict__ wt1,
                                              unsigned short* __restrict__ mh,
                                              unsigned short* __restrict__ ml) {
  int blk = blockIdx.x;
  int tt = threadIdx.x;
  if (blk < 576) {
    int idx = blk * 256 + tt;
    if (idx < 147456) {
      int ic = idx & 15;
      int oc = (idx >> 4) & 63;
      int g = idx >> 10;
      int tap = g % 9, icc = g / 9;
      float v = wm[(size_t)oc * 2304 + (icc * 16 + ic) * 9 + tap];
      short hi = f2bf(v);
      float rv = v - bf2f(hi);
      whiB[idx] = (unsigned short)hi;
      wloB[idx] = (unsigned short)f2bf(rv);
    }
  } else if (blk < 832) {
    int idx = (blk - 576) * 256 + tt;  // 65536 total
    int ic = idx & 15, oc = (idx >> 4) & 255, icc = idx >> 12;
    wt1[idx] = (unsigned short)f2bf(wa[(size_t)oc * 256 + icc * 16 + ic]);
  } else {
    int idx = (blk - 832) * 256 + tt;  // 8192 total
    if (idx < 8192) {
      float v = means[idx];
      short hi = f2bf(v);
      mh[idx] = (unsigned short)hi;
      ml[idx] = (unsigned short)f2bf(v - bf2f(hi));
    }
  }
}

// ---------------- K1: conv3x3 via MFMA (split-bf16, 3 products) ----------------
// [R13 version, measured 80.2 us] grid 768 linear: b = i&7 (XCD affinity), h = i>>3.
// 192 thr = 3 waves; wave pt owns 32 px x 64 oc.
__global__ __launch_bounds__(192) void k_conv3(const unsigned short* __restrict__ xhi,
                                               const unsigned short* __restrict__ xlo,
                                               const unsigned short* __restrict__ whiB,
                                               const unsigned short* __restrict__ wloB,
                                               const float* __restrict__ bm,
                                               float* __restrict__ xe) {
  int i = blockIdx.x;
  int b = i & 7, h = i >> 3;
  __shared__ __align__(16) unsigned short lds[2 * 2 * 3 * 98 * 16];  // 37632 B
  int t = threadIdx.x;
  int pt = t >> 6, lane = t & 63;
  int hh = lane >> 5, j = lane & 31;
  int r = lane & 31;

  for (int e = t; e < 384; e += 192) {
    int slot = e >> 4, ic = e & 15;
    int bs = slot / 6, rem = slot % 6;
    int rr = rem >> 1, cc = rem & 1;
    lds[bs * 4704 + rr * 1568 + (cc ? 97 : 0) * 16 + ic] = 0;
  }

  f32x16 acc0 = {}, acc1 = {};

  auto stage = [&](int icc, int buf) {
#pragma unroll
    for (int k6 = 0; k6 < 6; ++k6) {
      int u = t + k6 * 192;
      int s = u / 576;
      int rem = u - s * 576;
      int rr = rem / 192;
      int q = rem - rr * 192;
      int gr = h - 1 + rr;
      unsigned short* dst = &lds[(buf * 2 + s) * 4704 + rr * 1568 + 16 + q * 8];
      if (gr >= 0 && gr < 96) {
        const unsigned short* src =
            (s ? xlo : xhi) + ((((size_t)b * 96 + gr) * 16 + icc) * 1536 + q * 8);
        __builtin_amdgcn_global_load_lds((const __attribute__((address_space(1))) void*)src,
                                         (__attribute__((address_space(3))) void*)dst, 16, 0, 0);
      } else {
        *(s8v*)dst = (s8v){0, 0, 0, 0, 0, 0, 0, 0};
      }
    }
  };

  auto compute = [&](int icc, int buf) {
    const unsigned short* lbase = lds + buf * 9408;
    const unsigned short* wb = whiB + (size_t)icc * 9216;
    const unsigned short* wl = wloB + (size_t)icc * 9216;
#pragma unroll
    for (int kh = 0; kh < 3; ++kh)
#pragma unroll
      for (int kw = 0; kw < 3; ++kw) {
        int tap = kh * 3 + kw;
        int aidx = kh * 1568 + (pt * 32 + r + kw) * 16 + hh * 8;
        s8v a_hi = *(const s8v*)(lbase + aidx);
        s8v a_lo = *(const s8v*)(lbase + 4704 + aidx);
        int woff = tap * 1024 + j * 16 + hh * 8;
        s8v b_hi0 = *(const s8v*)(wb + woff);
        s8v b_lo0 = *(const s8v*)(wl + woff);
        s8v b_hi1 = *(const s8v*)(wb + woff + 512);
        s8v b_lo1 = *(const s8v*)(wl + woff + 512);
        acc0 = __builtin_amdgcn_mfma_f32_32x32x16_bf16(a_hi, b_hi0, acc0, 0, 0, 0);
        acc0 = __builtin_amdgcn_mfma_f32_32x32x16_bf16(a_hi, b_lo0, acc0, 0, 0, 0);
        acc0 = __builtin_amdgcn_mfma_f32_32x32x16_bf16(a_lo, b_hi0, acc0, 0, 0, 0);
        acc1 = __builtin_amdgcn_mfma_f32_32x32x16_bf16(a_hi, b_hi1, acc1, 0, 0, 0);
        acc1 = __builtin_amdgcn_mfma_f32_32x32x16_bf16(a_hi, b_lo1, acc1, 0, 0, 0);
        acc1 = __builtin_amdgcn_mfma_f32_32x32x16_bf16(a_lo, b_hi1, acc1, 0, 0, 0);
      }
  };

  stage(0, 0);
  __syncthreads();
#pragma unroll 1
  for (int icc = 0; icc < 16; ++icc) {
    int buf = icc & 1;
    if (icc < 15) stage(icc + 1, buf ^ 1);
    compute(icc, buf);
    __syncthreads();
  }

  float bv0 = bm[j], bv1 = bm[32 + j];
#pragma unroll
  for (int reg = 0; reg < 16; ++reg) {
    int prow = (reg & 3) + 8 * (reg >> 2) + 4 * hh;
    size_t rowbase = ((size_t)b * L + h * 96 + pt * 32 + prow) * 64;
    xe[rowbase + j] = acc0[reg] + bv0;
    xe[rowbase + 32 + j] = acc1[reg] + bv1;
  }
}

// ---------------- K2: conv1x1 via MFMA bf16 (no LDS, no barriers) ----------------
__global__ __launch_bounds__(384) void k_conv1(const unsigned short* __restrict__ xhi,
                                               const unsigned short* __restrict__ wt1,
                                               const float* __restrict__ ba,
                                               unsigned short* __restrict__ yeb) {
  int h = blockIdx.x, b = blockIdx.y;
  int t = threadIdx.x;
  int wave = t >> 6, lane = t & 63;
  int pt = wave % 3, ot = wave / 3;
  int hh = lane >> 5, j = lane & 31;
  int r = lane & 31;

  f32x16 acc[4] = {};
  const unsigned short* abase =
      xhi + (((size_t)b * 96 + h) * 16) * 1536 + (pt * 32 + r) * 16 + hh * 8;
  const unsigned short* bbase = wt1 + (ot * 128 + j) * 16 + hh * 8;
#pragma unroll 2
  for (int icc = 0; icc < 16; ++icc) {
    s8v av = *(const s8v*)(abase + icc * 1536);
    const unsigned short* bp = bbase + icc * 4096;
#pragma unroll
    for (int tile = 0; tile < 4; ++tile) {
      s8v bv = *(const s8v*)(bp + tile * 512);
      acc[tile] = __builtin_amdgcn_mfma_f32_32x32x16_bf16(av, bv, acc[tile], 0, 0, 0);
    }
  }
#pragma unroll
  for (int tile = 0; tile < 4; ++tile) {
    int oc = ot * 128 + tile * 32 + j;
    float bias = ba[oc];
#pragma unroll
    for (int reg = 0; reg < 16; ++reg) {
      int prow = (reg & 3) + 8 * (reg >> 2) + 4 * hh;
      yeb[((size_t)b * L + h * 96 + pt * 32 + prow) * 256 + oc] =
          (unsigned short)f2bf(acc[tile][reg] + bias);
    }
  }
}

// ---------------- K3: buckets via MFMA (split-bf16, 3 products) + shfl argmax ----------------
__global__ __launch_bounds__(192) void k_bucket(const float* __restrict__ xe,
                                                const unsigned short* __restrict__ mh,
                                                const unsigned short* __restrict__ ml,
                                                int* __restrict__ buckets) {
  int i = blockIdx.x;
  int b = i & 7, h = i >> 3;
  int t = threadIdx.x;
  int pt = t >> 6, lane = t & 63;
  int hh = lane >> 5, j = lane & 31;
  int r = lane & 31;

  s8v ah[4], al[4];
  const float* xrow = xe + ((size_t)b * L + h * 96 + pt * 32 + r) * 64 + hh * 8;
#pragma unroll
  for (int kc = 0; kc < 4; ++kc) {
    f32x4 v0 = *(const f32x4*)(xrow + kc * 16);
    f32x4 v1 = *(const f32x4*)(xrow + kc * 16 + 4);
#pragma unroll
    for (int e = 0; e < 4; ++e) {
      float x0 = v0[e];
      short h0 = f2bf(x0);
      ah[kc][e] = h0;
      al[kc][e] = f2bf(x0 - bf2f(h0));
      float x1 = v1[e];
      short h1 = f2bf(x1);
      ah[kc][e + 4] = h1;
      al[kc][e + 4] = f2bf(x1 - bf2f(h1));
    }
  }

  f32x16 acc[4] = {};
#pragma unroll
  for (int kc = 0; kc < 4; ++kc) {
#pragma unroll
    for (int ct = 0; ct < 4; ++ct) {
      const unsigned short* mp = mh + (size_t)(ct * 32 + j) * 64 + kc * 16 + hh * 8;
      const unsigned short* lp = ml + (size_t)(ct * 32 + j) * 64 + kc * 16 + hh * 8;
      s8v bh = *(const s8v*)mp;
      s8v bl = *(const s8v*)lp;
      acc[ct] = __builtin_amdgcn_mfma_f32_32x32x16_bf16(ah[kc], bh, acc[ct], 0, 0, 0);
      acc[ct] = __builtin_amdgcn_mfma_f32_32x32x16_bf16(ah[kc], bl, acc[ct], 0, 0, 0);
      acc[ct] = __builtin_amdgcn_mfma_f32_32x32x16_bf16(al[kc], bh, acc[ct], 0, 0, 0);
    }
  }

  int* bb = buckets + b * L + h * 96 + pt * 32;
#pragma unroll
  for (int reg = 0; reg < 16; ++reg) {
    float best = acc[0][reg];
    int bc = j;
#pragma unroll
    for (int ct = 1; ct < 4; ++ct) {
      float v = acc[ct][reg];
      int c = ct * 32 + j;
      if (v > best || (v == best && c < bc)) { best = v; bc = c; }
    }
#pragma unroll
    for (int m = 1; m <= 16; m <<= 1) {
      float ov = __shfl_xor(best, m);
      int oc = __shfl_xor(bc, m);
      if (ov > best || (ov == best && oc < bc)) { best = ov; bc = oc; }
    }
    if (j == 0) {
      int prow = (reg & 3) + 8 * (reg >> 2) + 4 * hh;
      bb[prow] = bc;
    }
  }
}

// ---------------- K4: parallel stable counting sort ----------------
#define SCH 256
#define CHL 36
__global__ __launch_bounds__(256) void k_sort(const int* __restrict__ buckets,
                                              int* __restrict__ sidx) {
  int b = blockIdx.x, t = threadIdx.x;
  __shared__ int keys_s[L];
  __shared__ unsigned short cnt_s[SCH][130];
  __shared__ int halfsum0[NCLUST];
  __shared__ int keytotal[NCLUST];
  __shared__ int keybase[NCLUST];
  const int* bk = buckets + b * L;
  for (int i = t; i < L; i += SCH) keys_s[i] = bk[i];
  for (int i = 0; i < 130; ++i) cnt_s[t][i] = 0;
  __syncthreads();
  {
    int base = t * CHL;
    for (int i = 0; i < CHL; ++i) cnt_s[t][keys_s[base + i]]++;
  }
  __syncthreads();
  {
    int kkey = t & 127, h = t >> 7;
    int c0 = h * 128;
    int run = 0;
    for (int c = 0; c < 128; ++c) {
      int v = cnt_s[c0 + c][kkey];
      cnt_s[c0 + c][kkey] = (unsigned short)run;
      run += v;
    }
    if (h == 0) halfsum0[kkey] = run;
    else keytotal[kkey] = run;
  }
  __syncthreads();
  if (t < NCLUST) keytotal[t] += halfsum0[t];
  __syncthreads();
  if (t == 0) {
    int s = 0;
    for (int i = 0; i < NCLUST; ++i) { keybase[i] = s; s += keytotal[i]; }
  }
  __syncthreads();
  {
    int h = t >> 7;
    int base = t * CHL;
    int* sb = sidx + b * L;
    for (int i = 0; i < CHL; ++i) {
      int kkey = keys_s[base + i];
      int pos = keybase[kkey] + (h ? halfsum0[kkey] : 0) + cnt_s[t][kkey];
      cnt_s[t][kkey]++;
      sb[pos] = base + i;
    }
  }
}

// ---------------- K5: gather + normalize -> xk (bf16 swizzled), yt (bf16 V^T tiles) ----------------
__global__ __launch_bounds__(256) void k_gather(const float* __restrict__ xe,
                                                const unsigned short* __restrict__ yeb,
                                                const int* __restrict__ sidx,
                                                unsigned short* __restrict__ xk,
                                                unsigned short* __restrict__ yt,
                                                float* __restrict__ norms) {
  int it = blockIdx.x, b = blockIdx.y;
  int i0 = it * 64;
  __shared__ float x_s[64 * 65];
  __shared__ unsigned short y_s[16 * 260];
  __shared__ int idx_s[64];
  __shared__ float scale_s[64];
  int t = threadIdx.x;
  if (t < 64) idx_s[t] = sidx[b * L + i0 + t];
  __syncthreads();
  for (int e = t; e < 4096; e += 256) {
    int i = e >> 6, d = e & 63;
    x_s[i * 65 + d] = xe[((size_t)b * L + idx_s[i]) * 64 + d];
  }
  __syncthreads();
  if (t < 64) {
    float s = 0.f;
    const float* xr = &x_s[t * 65];
#pragma unroll
    for (int d = 0; d < 64; ++d) s += xr[d] * xr[d];
    float n = fmaxf(sqrtf(s), 5e-5f);
    norms[b * L + i0 + t] = n;
    scale_s[t] = 1.0f / n;
  }
  __syncthreads();
  for (int e = t; e < 4096; e += 256) {
    int i = e >> 6, d = e & 63;
    int ig = i0 + i;
    int db = (((d >> 3) ^ (ig & 7)) << 3) | (d & 7);
    xk[((size_t)b * L + ig) * 64 + db] = (unsigned short)f2bf(x_s[i * 65 + d] * scale_s[i]);
  }
  for (int tile = 0; tile < 4; ++tile) {
    for (int e = t; e < 4096; e += 256) {
      int i16 = e >> 8, c = e & 255;
      y_s[i16 * 260 + c] = yeb[((size_t)b * L + idx_s[tile * 16 + i16]) * 256 + c];
    }
    __syncthreads();
    size_t tb = (size_t)b * L * 256 + (size_t)((i0 >> 4) + tile) * 4096;
    for (int e = t; e < 4096; e += 256) {
      int c = e >> 4, k16 = e & 15;
      int sw = ((((k16 >> 2) ^ ((c >> 2) & 3)) << 2) | (k16 & 3));
      yt[tb + c * 16 + sw] = y_s[k16 * 260 + c];
    }
    __syncthreads();
  }
}

// ---------------- K6: flash MFMA attention ----------------
// grid (512) linear: b = i&7 (XCD affinity), k = i>>3. 576 thr = 9 waves.
__global__ __launch_bounds__(576, 1) void k_attn(const unsigned short* __restrict__ xk,
                                                 const unsigned short* __restrict__ yt,
                                                 const float* __restrict__ norms,
                                                 const int* __restrict__ sidx,
                                                 float* __restrict__ retb) {
  int i = blockIdx.x;
  int b = i & 7, k = i >> 3;
  __shared__ __align__(16) char lds[40960];
  int t = threadIdx.x;
  int lane = t & 63;
  int g = lane >> 4, kr = lane & 15;
  int kbase = k * WIN;
  int qr0 = kbase + (t >> 6) * 16;
  int qrow = qr0 + kr;

  s8v qf[2];
#pragma unroll
  for (int s = 0; s < 2; ++s) {
    int blk = (4 * s + g) ^ (qrow & 7);
    qf[s] = *(const s8v*)(xk + ((size_t)b * L + qrow) * 64 + blk * 8);
  }
  float qn = norms[(size_t)b * L + qrow];

  f32x4 acc[16];
#pragma unroll
  for (int nf = 0; nf < 16; ++nf) acc[nf] = (f32x4){0.f, 0.f, 0.f, 0.f};
  float runm = -3e38f, runsum = 0.f;

  auto stage = [&](int c, int buf) {
    char* kb = lds + buf * 20480;
    char* vb = kb + 4096;
    for (int e = t; e < 1280; e += 576) {
      if (e < 256) {
        int key32 = e >> 3;
        if (c == 13 && key32 >= 16) continue;
        int j = c * 32 + key32;
        int r = (j >= 288) ? 2 : (j >= 144) ? 1 : 0;
        int kk = (r == 0) ? k : (r == 1) ? ((k + 63) & 63) : ((k + 1) & 63);
        int phys = kk * WIN + (j - r * 144);
        const char* gp = (const char*)xk + (((size_t)b * L + phys) * 64 + (e & 7) * 8) * 2;
        __builtin_amdgcn_global_load_lds((const __attribute__((address_space(1))) void*)gp,
                                         (__attribute__((address_space(3))) void*)(kb + e * 16),
                                         16, 0, 0);
      } else {
        int u = e - 256;
        int f = u >> 9;
        if (c == 13 && f == 1) continue;
        int j0 = c * 32 + f * 16;
        int r = (j0 >= 288) ? 2 : (j0 >= 144) ? 1 : 0;
        int kk = (r == 0) ? k : (r == 1) ? ((k + 63) & 63) : ((k + 1) & 63);
        int rowbase = kk * WIN + (j0 - r * 144);
        const char* gp = (const char*)yt + ((size_t)b * L + rowbase) * 512 + (size_t)(u & 511) * 16;
        __builtin_amdgcn_global_load_lds((const __attribute__((address_space(1))) void*)gp,
                                         (__attribute__((address_space(3))) void*)(vb + u * 16),
                                         16, 0, 0);
      }
    }
  };

  auto compute = [&](int c, int buf) {
    char* kb = lds + buf * 20480;
    char* vb = kb + 4096;
    int nm = (c == 13) ? 1 : 2;
    f32x4 sa[2];
    sa[0] = (f32x4){0.f, 0.f, 0.f, 0.f};
    sa[1] = (f32x4){0.f, 0.f, 0.f, 0.f};
#pragma unroll
    for (int m = 0; m < 2; ++m)
      if (m < nm) {
        int row32 = m * 16 + kr;
#pragma unroll
        for (int s = 0; s < 2; ++s) {
          int off = row32 * 128 + (((4 * s + g) ^ (row32 & 7)) * 16);
          s8v kf = *(const s8v*)(kb + off);
          sa[m] = __builtin_amdgcn_mfma_f32_16x16x32_bf16(kf, qf[s], sa[m], 0, 0, 0);
        }
      }
    float p[2][4];
    float mx = -3e38f;
#pragma unroll
    for (int m = 0; m < 2; ++m)
#pragma unroll
      for (int r = 0; r < 4; ++r) {
        float v = (m < nm) ? sa[m][r] * qn : -3e38f;
        p[m][r] = v;
        mx = fmaxf(mx, v);
      }
    mx = fmaxf(mx, __shfl_xor(mx, 16));
    mx = fmaxf(mx, __shfl_xor(mx, 32));
    if (!__all(mx <= runm + 8.f)) {
      float newm = fmaxf(runm, mx);
      float corr = __expf(runm - newm);
      runm = newm;
      runsum *= corr;
      float f0 = __shfl(corr, 4 * g + 0);
      float f1 = __shfl(corr, 4 * g + 1);
      float f2 = __shfl(corr, 4 * g + 2);
      float f3 = __shfl(corr, 4 * g + 3);
#pragma unroll
      for (int nf = 0; nf < 16; ++nf) {
        acc[nf][0] *= f0; acc[nf][1] *= f1; acc[nf][2] *= f2; acc[nf][3] *= f3;
      }
    }
    float psum = 0.f;
#pragma unroll
    for (int m = 0; m < 2; ++m)
#pragma unroll
      for (int r = 0; r < 4; ++r) {
        float pv = __expf(p[m][r] - runm);
        p[m][r] = pv;
        psum += pv;
      }
    runsum += psum;
    s8v pa;
#pragma unroll
    for (int e2 = 0; e2 < 8; ++e2) pa[e2] = f2bf(p[e2 >> 2][e2 & 3]);
#pragma unroll
    for (int nf = 0; nf < 16; ++nf) {
      int cch = nf * 16 + kr;
      int grp = g ^ ((cch >> 2) & 3);
      s4v lo = *(const s4v*)(vb + cch * 32 + grp * 8);
      s4v hi = *(const s4v*)(vb + 8192 + cch * 32 + grp * 8);
      s8v bfv = __builtin_shufflevector(lo, hi, 0, 1, 2, 3, 4, 5, 6, 7);
      acc[nf] = __builtin_amdgcn_mfma_f32_16x16x32_bf16(pa, bfv, acc[nf], 0, 0, 0);
    }
  };

  stage(0, 0);
  __syncthreads();
  for (int c = 0; c < 14; ++c) {
    if (c < 13) stage(c + 1, (c + 1) & 1);
    compute(c, c & 1);
    __syncthreads();
  }

  runsum += __shfl_xor(runsum, 16);
  runsum += __shfl_xor(runsum, 32);
  float inv = 1.0f / runsum;
  float invr[4];
  int lorig[4];
#pragma unroll
  for (int r = 0; r < 4; ++r) {
    invr[r] = __shfl(inv, 4 * g + r);
    lorig[r] = sidx[b * L + qr0 + 4 * g + r];
  }
#pragma unroll
  for (int nf = 0; nf < 16; ++nf)
#pragma unroll
    for (int r = 0; r < 4; ++r)
      retb[((size_t)b * L + lorig[r]) * 256 + nf * 16 + kr] = acc[nf][r] * invr[r];
}

// ---------------- K7: transpose + residual (32 l x 64 c tiles) ----------------
__global__ __launch_bounds__(256) void k_final(const float* __restrict__ in,
                                               const float* __restrict__ retb,
                                               float* __restrict__ out) {
  int lt = blockIdx.x, ct = blockIdx.y, b = blockIdx.z;
  int l0 = lt * 32, c0 = ct * 64;
  __shared__ float t_s[32][66];
  int t = threadIdx.x;
  // load 32 l-rows x 64 c (f32x4 per thread x 2)
  {
    int i = t >> 3, c4 = t & 7;  // i: l-row, c4: 16-col group... 8 groups x 8? use 2 passes
    for (int p = 0; p < 2; ++p) {
      int idx = t + p * 256;       // 512 f32x4 loads total
      int li = idx >> 4, cg = idx & 15;
      f32x4 v = *(const f32x4*)&retb[((size_t)b * L + l0 + li) * 256 + c0 + cg * 4];
      t_s[li][cg * 4 + 0] = v[0];
      t_s[li][cg * 4 + 1] = v[1];
      t_s[li][cg * 4 + 2] = v[2];
      t_s[li][cg * 4 + 3] = v[3];
    }
  }
  __syncthreads();
  // write 64 c-rows x 32 l, vectorized f32x4 on l
  for (int p = 0; p < 2; ++p) {
    int idx = t + p * 256;        // 512 f32x4 stores total
    int ci = idx >> 3, lg = idx & 7;
    size_t o = ((size_t)b * CC + c0 + ci) * L + l0 + lg * 4;
    f32x4 iv = *(const f32x4*)&in[o];
    f32x4 ov;
    ov[0] = iv[0] + 0.1f * t_s[lg * 4 + 0][ci];
    ov[1] = iv[1] + 0.1f * t_s[lg * 4 + 1][ci];
    ov[2] = iv[2] + 0.1f * t_s[lg * 4 + 2][ci];
    ov[3] = iv[3] + 0.1f * t_s[lg * 4 + 3][ci];
    *(f32x4*)&out[o] = ov;
  }
}

extern "C" void kernel_launch(void* const* d_in, const int* in_sizes, int n_in,
                              void* d_out, int out_size, void* d_ws, size_t ws_size,
                              hipStream_t stream) {
  const float* input = (const float*)d_in[0];
  const float* wm = (const float*)d_in[1];
  const float* bm = (const float*)d_in[2];
  const float* wa = (const float*)d_in[3];
  const float* ba = (const float*)d_in[4];
  const float* means = (const float*)d_in[5];
  float* out = (float*)d_out;

  float* ws = (float*)d_ws;
  float* x_embed = ws;                                      // 4,718,592 f
  float* y_embed = ws + 4718592ull;                         // 18,874,368 f (aliased: xhi/yeb, retb)
  float* retb = y_embed;
  unsigned short* xk = (unsigned short*)(ws + 23592960ull); // 4,718,592 bf16 (aliased: w bufs)
  unsigned short* yt = (unsigned short*)(ws + 25952256ull); // 18,874,368 bf16
  float* norms = ws + 35389440ull;                          // 73,728 f
  int* buckets = (int*)(ws + 35463168ull);                  // 73,728 i
  int* sidx = buckets + 73728;                              // 73,728 i
  unsigned short* xhi = (unsigned short*)y_embed;           // 18,874,368 bf16 (first half)
  unsigned short* xlo = xhi + 18874368ull;                  // second half; becomes yeb
  unsigned short* yeb = xlo;
  unsigned short* whiB = xk;                                // 294,912 bf16
  unsigned short* wloB = whiB + 294912ull;                  // 294,912 bf16
  unsigned short* wt1 = wloB + 294912ull;                   // 65,536 bf16
  unsigned short* mh = wt1 + 65536ull;                      // 8,192 bf16
  unsigned short* mlp = mh + 8192ull;                       // 8,192 bf16

  k_isplit<<<dim3(96, 16, 8), 256, 0, stream>>>(input, xhi, xlo);
  k_prep<<<dim3(864), 256, 0, stream>>>(wm, wa, means, whiB, wloB, wt1, mh, mlp);
  k_conv3<<<dim3(768), 192, 0, stream>>>(xhi, xlo, whiB, wloB, bm, x_embed);
  k_conv1<<<dim3(96, 8), 384, 0, stream>>>(xhi, wt1, ba, yeb);
  k_bucket<<<dim3(768), 192, 0, stream>>>(x_embed, mh, mlp, buckets);
  k_sort<<<dim3(8), 256, 0, stream>>>(buckets, sidx);
  k_gather<<<dim3(144, 8), 256, 0, stream>>>(x_embed, yeb, sidx, xk, yt, norms);
  k_attn<<<dim3(512), 576, 0, stream>>>(xk, yt, norms, sidx, retb);
  k_final<<<dim3(288, 4, 8), 256, 0, stream>>>(input, retb, out);
}